// Round 5
// baseline (592.448 us; speedup 1.0000x reference)
//
#include <hip/hip_runtime.h>
#include <hip/hip_bf16.h>

// Problem constants (B=2, S=4096 -> T=8192 tokens)
#define TT 8192
#define DD 1024
#define HH 2048
#define EE 8

typedef __bf16 bf16x8 __attribute__((ext_vector_type(8)));
typedef float floatx4 __attribute__((ext_vector_type(4)));
typedef short shortx8 __attribute__((ext_vector_type(8)));

// float -> bf16 bits, round-to-nearest-even
__device__ __forceinline__ short f2bf(float f) {
  unsigned u = __float_as_uint(f);
  u += 0x7fffu + ((u >> 16) & 1u);
  return (short)(u >> 16);
}

__device__ __forceinline__ float bf2f(short s) {
  return __uint_as_float(((unsigned)(unsigned short)s) << 16);
}

// async global->LDS, 16B per lane; LDS dest = wave-uniform base + lane*16
__device__ __forceinline__ void gld16(const void* g, void* l) {
  __builtin_amdgcn_global_load_lds((const __attribute__((address_space(1))) void*)g,
                                   (__attribute__((address_space(3))) void*)l, 16, 0, 0);
}

// ---------------- Router: logits, top-2, softmax, expert lists, fused x->bf16 ----------------
// Also emits per-token slot packs (e<<13|pos) + coef pairs for the combine kernel.
__global__ __launch_bounds__(256) void router_kernel(
    const float* __restrict__ x, const float* __restrict__ rw,
    int* __restrict__ cpad, float* __restrict__ ppad,
    int* __restrict__ list_token, float* __restrict__ list_coef,
    int* __restrict__ tokpk, float* __restrict__ tokcf,
    short* __restrict__ xb)
{
  __shared__ int   sE0[32], sE1[32], lcnt[EE], sbase[EE], lp0[32], lp1[32];
  __shared__ float sG0[32], sG1[32], sP[EE];
  const int tid = threadIdx.x;
  if (tid < EE) { sP[tid] = 0.f; lcnt[tid] = 0; }
  __syncthreads();
  const int lane = tid & 63, wv = tid >> 6;
  const int t0 = blockIdx.x * 32;
  for (int ti = 0; ti < 8; ++ti) {
    const int s = wv * 8 + ti;
    const int t = t0 + s;
    float sc[EE];
#pragma unroll
    for (int e = 0; e < EE; ++e) sc[e] = 0.f;
#pragma unroll
    for (int j = 0; j < 4; ++j) {
      float4 xv = *(const float4*)(x + (size_t)t * DD + j * 256 + lane * 4);
#pragma unroll
      for (int e = 0; e < EE; ++e) {
        float4 rv = *(const float4*)(rw + e * DD + j * 256 + lane * 4);
        sc[e] += xv.x * rv.x + xv.y * rv.y + xv.z * rv.z + xv.w * rv.w;
      }
      if (xb) {  // fused fp32 -> bf16 conversion of x
        short4 sv = make_short4(f2bf(xv.x), f2bf(xv.y), f2bf(xv.z), f2bf(xv.w));
        *(short4*)(xb + (size_t)t * DD + j * 256 + lane * 4) = sv;
      }
    }
#pragma unroll
    for (int off = 32; off > 0; off >>= 1)
#pragma unroll
      for (int e = 0; e < EE; ++e)
        sc[e] += __shfl_down(sc[e], off);
    if (lane == 0) {
      int i0 = 0; float l0 = sc[0];
      for (int e = 1; e < EE; ++e) if (sc[e] > l0) { l0 = sc[e]; i0 = e; }
      int i1 = -1; float l1 = -3.4e38f;
      for (int e = 0; e < EE; ++e) if (e != i0 && sc[e] > l1) { l1 = sc[e]; i1 = e; }
      const float g0 = 1.f / (1.f + __expf(l1 - l0));
      float pr[EE]; float sum = 0.f;
      for (int e = 0; e < EE; ++e) { pr[e] = __expf(sc[e] - l0); sum += pr[e]; }
      const float inv = 1.f / sum;
      for (int e = 0; e < EE; ++e) atomicAdd(&sP[e], pr[e] * inv);
      sE0[s] = i0; sE1[s] = i1; sG0[s] = g0; sG1[s] = 1.f - g0;
    }
  }
  __syncthreads();
  if (tid < 32) {
    lp0[tid] = atomicAdd(&lcnt[sE0[tid]], 1);
    lp1[tid] = atomicAdd(&lcnt[sE1[tid]], 1);
  }
  __syncthreads();
  if (tid < EE) {
    sbase[tid] = atomicAdd(&cpad[tid * 16], lcnt[tid]);
    atomicAdd(&ppad[tid * 16], sP[tid]);
  }
  __syncthreads();
  if (tid < 32) {
    int e0 = sE0[tid], e1 = sE1[tid], t = t0 + tid;
    int p0 = sbase[e0] + lp0[tid];
    int p1 = sbase[e1] + lp1[tid];
    list_token[e0 * TT + p0] = t; list_coef[e0 * TT + p0] = sG0[tid];
    list_token[e1 * TT + p1] = t; list_coef[e1 * TT + p1] = sG1[tid];
    tokpk[t * 2]     = (e0 << 13) | p0;  tokcf[t * 2]     = sG0[tid];
    tokpk[t * 2 + 1] = (e1 << 13) | p1;  tokcf[t * 2 + 1] = sG1[tid];
  }
}

// ---------------- Aux loss + prefix-sum offsets ----------------
__global__ void aux_kernel(const int* __restrict__ cpad, const float* __restrict__ ppad,
                           int* __restrict__ offsets, float* __restrict__ out_aux)
{
  if (threadIdx.x == 0) {
    float aux = 0.f; int off = 0;
    for (int e = 0; e < EE; ++e) {
      aux += ((float)cpad[e * 16] / (float)TT) * (ppad[e * 16] / (float)TT);
      offsets[e] = off; off += cpad[e * 16];
    }
    *out_aux = aux * (float)EE;
  }
}

// ---------------- fused w1+w3 convert+transpose -> W13T interleaved bf16 ----------------
// w1 col c -> W13T row 2*(c&~31)+(c&31); w3 col c -> +32.  grid: (HH/64, DD/64, 2*EE)
__global__ __launch_bounds__(256) void convt13_kernel(const float* __restrict__ w1,
                                                      const float* __restrict__ w3,
                                                      short* __restrict__ out)
{
  __shared__ short T[64 * 74];
  const int t = threadIdx.x;
  const int z = blockIdx.z;
  const int is3 = (z >= EE) ? 1 : 0;
  const int e = is3 ? (z - EE) : z;
  const float* in = (is3 ? w3 : w1) + (size_t)e * DD * HH;
  short* o = out + (size_t)e * DD * HH * 2;
  const int c0 = blockIdx.x * 64, r0 = blockIdx.y * 64;
#pragma unroll
  for (int p = 0; p < 4; ++p) {
    int r = p * 16 + (t >> 4), c4 = (t & 15) * 4;
    float4 v = *(const float4*)(in + (size_t)(r0 + r) * HH + c0 + c4);
    short4 s = make_short4(f2bf(v.x), f2bf(v.y), f2bf(v.z), f2bf(v.w));
    *(short4*)&T[r * 74 + c4] = s;
  }
  __syncthreads();
#pragma unroll
  for (int q = 0; q < 2; ++q) {
    int u = q * 256 + t;
    int oc = u >> 3, k8 = (u & 7) * 8;
    shortx8 s;
#pragma unroll
    for (int j = 0; j < 8; ++j) s[j] = T[(k8 + j) * 74 + oc];
    int c = c0 + oc;
    int grow = 2 * (c & ~31) + (c & 31) + (is3 ? 32 : 0);
    *(shortx8*)&o[(size_t)grow * DD + r0 + k8] = s;
  }
}

// ---------------- generic convert+transpose: in [R][C] fp32 -> out [C][R] bf16 (w2) -----------
__global__ __launch_bounds__(256) void convt_kernel(const float* __restrict__ in, short* __restrict__ out,
                                                    int R, int C)
{
  __shared__ short T[64 * 74];
  const int t = threadIdx.x;
  in  += (size_t)blockIdx.z * R * C;
  out += (size_t)blockIdx.z * R * C;
  const int c0 = blockIdx.x * 64, r0 = blockIdx.y * 64;
#pragma unroll
  for (int p = 0; p < 4; ++p) {
    int r = p * 16 + (t >> 4), c4 = (t & 15) * 4;
    float4 v = *(const float4*)(in + (size_t)(r0 + r) * C + c0 + c4);
    short4 s = make_short4(f2bf(v.x), f2bf(v.y), f2bf(v.z), f2bf(v.w));
    *(short4*)&T[r * 74 + c4] = s;
  }
  __syncthreads();
#pragma unroll
  for (int q = 0; q < 2; ++q) {
    int u = q * 256 + t;
    int oc = u >> 3, k8 = (u & 7) * 8;
    shortx8 s;
#pragma unroll
    for (int j = 0; j < 8; ++j) s[j] = T[(k8 + j) * 74 + oc];
    *(shortx8*)&out[(size_t)(c0 + oc) * R + r0 + k8] = s;
  }
}

// =================== 8-phase 256x256 BK=64 pipelined MFMA core ==================
// (round-3 form, best measured. SQ_LDS_BANK_CONFLICT ~1.3e7 here is the structural
// global_load_lds write-side count — invariant to read swizzles, not a fixable stall.)

#define PH_BAR()  { __builtin_amdgcn_s_barrier(); __builtin_amdgcn_sched_barrier(0); }
#define WAITL0()  { asm volatile("s_waitcnt lgkmcnt(0)" ::: "memory"); __builtin_amdgcn_sched_barrier(0); }
#define WAITVN(n) { asm volatile("s_waitcnt vmcnt(" #n ")" ::: "memory"); __builtin_amdgcn_sched_barrier(0); }

template<int NT>
__device__ __forceinline__ void mma_core(char* SM, int tid,
    const char* a00, const char* a01, const char* a10, const char* a11,
    const char* b00, const char* b01, const char* b10, const char* b11,
    floatx4 (&acc)[8][4])
{
  const int lane = tid & 63, w = tid >> 6;
  const int l16 = lane & 15, quad = lane >> 4;
  const int wm = (w >> 2) & 1, wn = w & 3;
  // frag-read swizzle: col bits {4,5,6} ^= row(l16) bits {1,2,0}
  const int cx = (((l16 >> 1) & 1) << 4) | (((l16 >> 2) & 1) << 5) | ((l16 & 1) << 6);
  const int ck0 = (quad * 16) ^ cx;
  const int arb = (wm * 128 + l16) * 128;             // + mi*2048
  const int brb = 32768 + (wn * 64 + l16) * 128;      // + ni*2048
  const int wq = w * 2048;

#define SA_(u,h,p0,p1) { gld16((p0) + (size_t)(u) * 128, SM + (((u) & 1) << 16) + (h) * 16384 + wq); \
                         gld16((p1) + (size_t)(u) * 128, SM + (((u) & 1) << 16) + (h) * 16384 + wq + 1024); }
#define SB_(u,h,p0,p1) { gld16((p0) + (size_t)(u) * 128, SM + (((u) & 1) << 16) + 32768 + (h) * 16384 + wq); \
                         gld16((p1) + (size_t)(u) * 128, SM + (((u) & 1) << 16) + 32768 + (h) * 16384 + wq + 1024); }
#define LA_(mi) { a[mi][0] = *(const bf16x8*)(SM + cur + arb + (mi) * 2048 + ck0); \
                  a[mi][1] = *(const bf16x8*)(SM + cur + arb + (mi) * 2048 + (ck0 ^ 64)); }
#define LB_(ni) { b[ni][0] = *(const bf16x8*)(SM + cur + brb + (ni) * 2048 + ck0); \
                  b[ni][1] = *(const bf16x8*)(SM + cur + brb + (ni) * 2048 + (ck0 ^ 64)); }
#define MM_(mi,ni) { acc[mi][ni] = __builtin_amdgcn_mfma_f32_16x16x32_bf16(a[mi][0], b[ni][0], acc[mi][ni], 0, 0, 0); \
                     acc[mi][ni] = __builtin_amdgcn_mfma_f32_16x16x32_bf16(a[mi][1], b[ni][1], acc[mi][ni], 0, 0, 0); }

  // prologue: tile0 (A0,A1,B0,B1) + tile1 (A0,A1); wait tile0 landed (4 gld16 left in flight)
  SA_(0, 0, a00, a01); SA_(0, 1, a10, a11);
  SB_(0, 0, b00, b01); SB_(0, 1, b10, b11);
  SA_(1, 0, a00, a01); SA_(1, 1, a10, a11);
  WAITVN(4);
  __builtin_amdgcn_s_barrier();
  __builtin_amdgcn_sched_barrier(0);

#pragma unroll 2
  for (int t = 0; t < NT; ++t) {
    const int cur = (t & 1) << 16;
    bf16x8 a[8][2], b[4][2];
    // ---- P1: 12 ds_reads (a0-3, b0-1); stage B.h0(t+1) -> other buffer
    LA_(0) LA_(1) LA_(2) LA_(3) LB_(0) LB_(1)
    if (t + 1 < NT) SB_(t + 1, 0, b00, b01);
    PH_BAR(); WAITL0();
    __builtin_amdgcn_s_setprio(1);
    MM_(0,0) MM_(1,0) MM_(2,0) MM_(3,0) MM_(0,1) MM_(1,1) MM_(2,1) MM_(3,1)
    __builtin_amdgcn_s_setprio(0);
    PH_BAR();
    // ---- P2: 12 ds_reads (a4-7, b2-3); stage B.h1(t+1)
    LA_(4) LA_(5) LA_(6) LA_(7) LB_(2) LB_(3)
    if (t + 1 < NT) SB_(t + 1, 1, b10, b11);
    PH_BAR(); WAITL0();
    __builtin_amdgcn_s_setprio(1);
    MM_(4,2) MM_(5,2) MM_(6,2) MM_(7,2) MM_(4,3) MM_(5,3) MM_(6,3) MM_(7,3)
    __builtin_amdgcn_s_setprio(0);
    PH_BAR();
    // ---- P3: stage A.h0(t+2) into cur buffer
    if (t + 2 < NT) SA_(t + 2, 0, a00, a01);
    PH_BAR();
    __builtin_amdgcn_s_setprio(1);
    MM_(0,2) MM_(1,2) MM_(2,2) MM_(3,2) MM_(0,3) MM_(1,3) MM_(2,3) MM_(3,3)
    __builtin_amdgcn_s_setprio(0);
    PH_BAR();
    // ---- P4: stage A.h1(t+2); counted vmcnt(4)
    if (t + 2 < NT) SA_(t + 2, 1, a10, a11);
    PH_BAR();
    __builtin_amdgcn_s_setprio(1);
    MM_(4,0) MM_(5,0) MM_(6,0) MM_(7,0) MM_(4,1) MM_(5,1) MM_(6,1) MM_(7,1)
    __builtin_amdgcn_s_setprio(0);
    if (t + 2 < NT) { WAITVN(4); } else { WAITVN(0); }
    PH_BAR();
  }
#undef SA_
#undef SB_
#undef LA_
#undef LB_
#undef MM_
}

// ---------------- G1: H = silu(Xg @ w1) * (Xg @ w3), fused via W13T column-pair interleave ----
__global__ __launch_bounds__(512, 2) void g1p_kernel(
    const short* __restrict__ xb, const short* __restrict__ w13t,
    const int* __restrict__ cpad, const int* __restrict__ offsets,
    const int* __restrict__ list_token, short* __restrict__ Hbuf)
{
  const int lin = blockIdx.x + 16 * (blockIdx.y + 32 * blockIdx.z);
  const int xcd = lin & 7, c = lin >> 3;
  const int e = c >> 6, rb = (c >> 1) & 31, nb = (xcd << 1) | (c & 1);
  const int cnt = cpad[e * 16];
  if (rb * 256 >= cnt) return;
  __shared__ char SM[131072];
  const int tid = threadIdx.x;
  const int lane = tid & 63, w = tid >> 6;
  const int srow = lane >> 3;
  // staging-source swizzle matching frag-read swizzle
  const int scol = (((lane ^ (lane >> 4)) & 1) << 4)
                 | ((((lane >> 1) ^ (lane >> 5)) & 1) << 5)
                 | ((((lane >> 2) ^ (lane >> 3)) & 1) << 6);
  const int* lt = list_token + e * TT;
  const char* ap[2][2];
#pragma unroll
  for (int h = 0; h < 2; ++h)
#pragma unroll
    for (int i = 0; i < 2; ++i) {
      int gr = rb * 256 + h * 128 + (w * 2 + i) * 8 + srow;
      int tok = (gr < cnt) ? lt[gr] : lt[0];
      ap[h][i] = (const char*)xb + (size_t)tok * 2048 + scol;
    }
  const char* bb = (const char*)w13t + ((size_t)e * 4096 + nb * 256) * 2048
                 + (size_t)(w * 16 + srow) * 2048 + scol;
  floatx4 acc[8][4] = {};
  mma_core<16>(SM, tid, ap[0][0], ap[0][1], ap[1][0], ap[1][1],
               bb, bb + 8 * 2048, bb + 128 * 2048, bb + 136 * 2048, acc);
  const int off = offsets[e];
  const int l16 = lane & 15, quad = lane >> 4;
  const int wm = (w >> 2) & 1, wn = w & 3;
#pragma unroll
  for (int mi = 0; mi < 8; ++mi)
#pragma unroll
    for (int r = 0; r < 4; ++r) {
      int grow = rb * 256 + wm * 128 + mi * 16 + quad * 4 + r;
      if (grow < cnt) {
        size_t rowbase = (size_t)(off + grow) * HH + nb * 128 + wn * 32;
#pragma unroll
        for (int ni = 0; ni < 2; ++ni) {
          float aa = acc[mi][ni][r], bbv = acc[mi][ni + 2][r];
          float hv = aa / (1.f + __expf(-aa)) * bbv;
          Hbuf[rowbase + ni * 16 + l16] = f2bf(hv);
        }
      }
    }
}

// ---------------- G2: Obuf[slot] = (Hrows @ w2) via the same 256x256 8-phase core -------------
// w2t: [E][D][H] bf16 (n-major). A = Hbuf slots (compacted, no gather). AI=128 FLOP/B
// (vs 64 for the old 128x128 form — A-rows staged x4 instead of x8).
// grid: (DD/256=4, 32, 8); block 512. bf16 Obuf epilogue, no atomics.
__global__ __launch_bounds__(512, 2) void g2q_kernel(
    const short* __restrict__ Hbuf, const short* __restrict__ w2t,
    const int* __restrict__ cpad, const int* __restrict__ offsets,
    short* __restrict__ Obuf)
{
  const int nb = blockIdx.x, rb = blockIdx.y, e = blockIdx.z;
  const int cnt = cpad[e * 16];
  if (rb * 256 >= cnt) return;
  __shared__ char SM[131072];
  const int tid = threadIdx.x;
  const int lane = tid & 63, w = tid >> 6;
  const int srow = lane >> 3;
  const int scol = (((lane ^ (lane >> 4)) & 1) << 4)
                 | ((((lane >> 1) ^ (lane >> 5)) & 1) << 5)
                 | ((((lane >> 2) ^ (lane >> 3)) & 1) << 6);
  const int off = offsets[e];
  const char* ap[2][2];
#pragma unroll
  for (int h = 0; h < 2; ++h)
#pragma unroll
    for (int i = 0; i < 2; ++i) {
      int gr = rb * 256 + h * 128 + (w * 2 + i) * 8 + srow;
      int cg = (gr < cnt) ? gr : (cnt - 1);
      ap[h][i] = (const char*)Hbuf + (size_t)(off + cg) * 4096 + scol;
    }
  const char* bb = (const char*)w2t + ((size_t)e * DD + nb * 256) * 4096
                 + (size_t)(w * 16 + srow) * 4096 + scol;
  floatx4 acc[8][4] = {};
  mma_core<32>(SM, tid, ap[0][0], ap[0][1], ap[1][0], ap[1][1],
               bb, bb + 8 * 4096, bb + 128 * 4096, bb + 136 * 4096, acc);
  const int l16 = lane & 15, quad = lane >> 4;
  const int wm = (w >> 2) & 1, wn = w & 3;
#pragma unroll
  for (int mi = 0; mi < 8; ++mi)
#pragma unroll
    for (int r = 0; r < 4; ++r) {
      int grow = rb * 256 + wm * 128 + mi * 16 + quad * 4 + r;
      if (grow < cnt) {
        short* orow = Obuf + (size_t)(off + grow) * DD + nb * 256 + wn * 64;
#pragma unroll
        for (int ni = 0; ni < 4; ++ni)
          orow[ni * 16 + l16] = f2bf(acc[mi][ni][r]);
      }
    }
}

// ---------------- Combine: out[t] = c0*Obuf[slot0] + c1*Obuf[slot1] ----------------
// grid: TT/4 blocks x 256 threads; one wave per token, 16 els/lane in 2 passes
__global__ __launch_bounds__(256) void combine_kernel(
    const short* __restrict__ Obuf, const int* __restrict__ offsets,
    const int* __restrict__ tokpk, const float* __restrict__ tokcf,
    float* __restrict__ out)
{
  const int tid = threadIdx.x, lane = tid & 63, wv = tid >> 6;
  const int t = blockIdx.x * 4 + wv;
  const int pk0 = tokpk[t * 2], pk1 = tokpk[t * 2 + 1];
  const float c0 = tokcf[t * 2], c1 = tokcf[t * 2 + 1];
  const size_t r0 = (size_t)(offsets[pk0 >> 13] + (pk0 & 8191)) * DD;
  const size_t r1 = (size_t)(offsets[pk1 >> 13] + (pk1 & 8191)) * DD;
  float* orow = out + (size_t)t * DD;
#pragma unroll
  for (int p = 0; p < 2; ++p) {
    int cidx = p * 512 + lane * 8;
    shortx8 a = *(const shortx8*)(Obuf + r0 + cidx);
    shortx8 b = *(const shortx8*)(Obuf + r1 + cidx);
    float v[8];
#pragma unroll
    for (int j = 0; j < 8; ++j) v[j] = c0 * bf2f(a[j]) + c1 * bf2f(b[j]);
    *(float4*)(orow + cidx)     = make_float4(v[0], v[1], v[2], v[3]);
    *(float4*)(orow + cidx + 4) = make_float4(v[4], v[5], v[6], v[7]);
  }
}

// ================= FALLBACK (proven path, used if ws too small) =================
__global__ __launch_bounds__(256, 2) void g1s_kernel(
    const float* __restrict__ x, const float* __restrict__ w1, const float* __restrict__ w3,
    const int* __restrict__ cpad, const int* __restrict__ offsets,
    const int* __restrict__ list_token, short* __restrict__ Hbuf)
{
  const int e = blockIdx.z, rb = blockIdx.y, nb = blockIdx.x;
  const int cnt = cpad[e * 16];
  if (rb * 128 >= cnt) return;
  __shared__ short Asm[128 * 40];
  __shared__ short B1sm[128 * 40];
  __shared__ short B3sm[128 * 40];
  const int tid = threadIdx.x, lane = tid & 63, wv = tid >> 6;
  const int wm = (wv >> 1) * 64, wn = (wv & 1) * 64;
  const int quad = lane >> 4, l16 = lane & 15;
  floatx4 acc1[4][4] = {{{0.f}}};
  floatx4 acc3[4][4] = {{{0.f}}};
  const int ar = tid >> 3, ak = (tid & 7) * 4;
  const int bp = tid & 63, bq = tid >> 6;
  const int bswz = (bq ^ ((bp >> 2) & 3)) * 8;
  const int bo0 = (2 * bp) * 40 + bswz, bo1 = bo0 + 40;
  int aro[4], bro[4];
#pragma unroll
  for (int mi = 0; mi < 4; ++mi) aro[mi] = (wm + mi * 16 + l16) * 40 + quad * 8;
#pragma unroll
  for (int ni = 0; ni < 4; ++ni) {
    int nl = wn + ni * 16 + l16;
    bro[ni] = nl * 40 + ((quad ^ ((nl >> 3) & 3)) * 8);
  }
  int tok[4];
#pragma unroll
  for (int i = 0; i < 4; ++i) {
    int gr = rb * 128 + ar + 32 * i;
    tok[i] = (gr < cnt) ? list_token[e * TT + gr] : list_token[e * TT];
  }
  const float* w1e = w1 + (size_t)e * DD * HH + (size_t)nb * 128;
  const float* w3e = w3 + (size_t)e * DD * HH + (size_t)nb * 128;
  for (int k0 = 0; k0 < DD; k0 += 32) {
    __syncthreads();
#pragma unroll
    for (int i = 0; i < 4; ++i) {
      int r = ar + 32 * i;
      float4 v = *(const float4*)(x + (size_t)tok[i] * DD + k0 + ak);
      short4 sv = make_short4(f2bf(v.x), f2bf(v.y), f2bf(v.z), f2bf(v.w));
      *(short4*)&Asm[r * 40 + ak] = sv;
    }
    {
      float2 u[8];
#pragma unroll
      for (int j = 0; j < 8; ++j) u[j] = *(const float2*)(w1e + (size_t)(k0 + bq * 8 + j) * HH + 2 * bp);
      shortx8 p0, p1;
#pragma unroll
      for (int j = 0; j < 8; ++j) { p0[j] = f2bf(u[j].x); p1[j] = f2bf(u[j].y); }
      *(shortx8*)&B1sm[bo0] = p0; *(shortx8*)&B1sm[bo1] = p1;
    }
    {
      float2 u[8];
#pragma unroll
      for (int j = 0; j < 8; ++j) u[j] = *(const float2*)(w3e + (size_t)(k0 + bq * 8 + j) * HH + 2 * bp);
      shortx8 p0, p1;
#pragma unroll
      for (int j = 0; j < 8; ++j) { p0[j] = f2bf(u[j].x); p1[j] = f2bf(u[j].y); }
      *(shortx8*)&B3sm[bo0] = p0; *(shortx8*)&B3sm[bo1] = p1;
    }
    __syncthreads();
    bf16x8 af[4], b1f[4], b3f[4];
#pragma unroll
    for (int mi = 0; mi < 4; ++mi) af[mi] = *(const bf16x8*)&Asm[aro[mi]];
#pragma unroll
    for (int ni = 0; ni < 4; ++ni) {
      b1f[ni] = *(const bf16x8*)&B1sm[bro[ni]];
      b3f[ni] = *(const bf16x8*)&B3sm[bro[ni]];
    }
#pragma unroll
    for (int mi = 0; mi < 4; ++mi)
#pragma unroll
      for (int ni = 0; ni < 4; ++ni) {
        acc1[mi][ni] = __builtin_amdgcn_mfma_f32_16x16x32_bf16(af[mi], b1f[ni], acc1[mi][ni], 0, 0, 0);
        acc3[mi][ni] = __builtin_amdgcn_mfma_f32_16x16x32_bf16(af[mi], b3f[ni], acc3[mi][ni], 0, 0, 0);
      }
  }
  const int off = offsets[e];
#pragma unroll
  for (int mi = 0; mi < 4; ++mi)
#pragma unroll
    for (int r = 0; r < 4; ++r) {
      int row = wm + mi * 16 + quad * 4 + r;
      int grow = rb * 128 + row;
      if (grow < cnt) {
        size_t rowbase = (size_t)(off + grow) * HH + (size_t)nb * 128 + wn;
#pragma unroll
        for (int ni = 0; ni < 4; ++ni) {
          float a = acc1[mi][ni][r], b = acc3[mi][ni][r];
          float h = a / (1.f + __expf(-a)) * b;
          Hbuf[rowbase + ni * 16 + l16] = f2bf(h);
        }
      }
    }
}

__global__ __launch_bounds__(256, 2) void g2s_kernel(
    const short* __restrict__ Hbuf, const float* __restrict__ w2,
    const int* __restrict__ cpad, const int* __restrict__ offsets,
    const int* __restrict__ list_token, const float* __restrict__ list_coef,
    float* __restrict__ out)
{
  const int e = blockIdx.z, rb = blockIdx.y, nb = blockIdx.x;
  const int cnt = cpad[e * 16];
  if (rb * 128 >= cnt) return;
  __shared__ short Asm[128 * 40];
  __shared__ short Bsm[128 * 40];
  const int tid = threadIdx.x, lane = tid & 63, wv = tid >> 6;
  const int wm = (wv >> 1) * 64, wn = (wv & 1) * 64;
  const int quad = lane >> 4, l16 = lane & 15;
  floatx4 acc[4][4] = {{{0.f}}};
  const int ar = tid >> 3, ak = (tid & 7) * 4;
  const int bp = tid & 63, bq = tid >> 6;
  const int bswz = (bq ^ ((bp >> 2) & 3)) * 8;
  const int bo0 = (2 * bp) * 40 + bswz, bo1 = bo0 + 40;
  int aro[4], bro[4];
#pragma unroll
  for (int mi = 0; mi < 4; ++mi) aro[mi] = (wm + mi * 16 + l16) * 40 + quad * 8;
#pragma unroll
  for (int ni = 0; ni < 4; ++ni) {
    int nl = wn + ni * 16 + l16;
    bro[ni] = nl * 40 + ((quad ^ ((nl >> 3) & 3)) * 8);
  }
  const int off = offsets[e];
  size_t hrow[4];
#pragma unroll
  for (int i = 0; i < 4; ++i) {
    int gr = rb * 128 + ar + 32 * i;
    int cg = (gr < cnt) ? gr : (cnt - 1);
    hrow[i] = (size_t)(off + cg) * HH;
  }
  const float* w2e = w2 + (size_t)e * HH * DD + (size_t)nb * 128;
  for (int k0 = 0; k0 < HH; k0 += 32) {
    __syncthreads();
#pragma unroll
    for (int i = 0; i < 4; ++i) {
      int r = ar + 32 * i;
      short4 sv = *(const short4*)(Hbuf + hrow[i] + k0 + ak);
      *(short4*)&Asm[r * 40 + ak] = sv;
    }
    {
      float2 u[8];
#pragma unroll
      for (int j = 0; j < 8; ++j) u[j] = *(const float2*)(w2e + (size_t)(k0 + bq * 8 + j) * DD + 2 * bp);
      shortx8 p0, p1;
#pragma unroll
      for (int j = 0; j < 8; ++j) { p0[j] = f2bf(u[j].x); p1[j] = f2bf(u[j].y); }
      *(shortx8*)&Bsm[bo0] = p0; *(shortx8*)&Bsm[bo1] = p1;
    }
    __syncthreads();
    bf16x8 af[4], bf[4];
#pragma unroll
    for (int mi = 0; mi < 4; ++mi) af[mi] = *(const bf16x8*)&Asm[aro[mi]];
#pragma unroll
    for (int ni = 0; ni < 4; ++ni) bf[ni] = *(const bf16x8*)&Bsm[bro[ni]];
#pragma unroll
    for (int mi = 0; mi < 4; ++mi)
#pragma unroll
      for (int ni = 0; ni < 4; ++ni)
        acc[mi][ni] = __builtin_amdgcn_mfma_f32_16x16x32_bf16(af[mi], bf[ni], acc[mi][ni], 0, 0, 0);
  }
#pragma unroll
  for (int mi = 0; mi < 4; ++mi)
#pragma unroll
    for (int r = 0; r < 4; ++r) {
      int row = wm + mi * 16 + quad * 4 + r;
      int grow = rb * 128 + row;
      if (grow < cnt) {
        int tokid = list_token[e * TT + grow];
        float coef = list_coef[e * TT + grow];
        float* orow = out + (size_t)tokid * DD + (size_t)nb * 128 + wn;
#pragma unroll
        for (int ni = 0; ni < 4; ++ni)
          atomicAdd(&orow[ni * 16 + l16], coef * acc[mi][ni][r]);
      }
    }
}

extern "C" void kernel_launch(void* const* d_in, const int* in_sizes, int n_in,
                              void* d_out, int out_size, void* d_ws, size_t ws_size,
                              hipStream_t stream)
{
  const float* x  = (const float*)d_in[0];
  const float* rw = (const float*)d_in[1];
  const float* w1 = (const float*)d_in[2];
  const float* w3 = (const float*)d_in[3];
  const float* w2 = (const float*)d_in[4];
  float* out = (float*)d_out;

  char* ws = (char*)d_ws;
  int*   cpad      = (int*)(ws + 0);
  float* ppad      = (float*)(ws + 512);
  int*   offsets   = (int*)(ws + 1024);
  int*   list_tok  = (int*)(ws + 4096);
  float* list_coef = (float*)(ws + 4096 + EE * TT * 4);
  int*   tokpk     = (int*)(ws + 4096 + 2 * EE * TT * 4);            // 2*TT ints (64 KB)
  float* tokcf     = (float*)(ws + 4096 + 2 * EE * TT * 4 + 2 * TT * 4); // 2*TT floats (64 KB)

  // fast-path layout (bytes): hdr 1MB | W13T 64MB | XBF 16MB | HBUF 64.5MB
  // After g1p: first 32MB of W13T (experts 0-3) -> Obuf (bf16, 32MB);
  //            second 32MB (experts 4-7)        -> W2T (bf16, 32MB).
  const size_t OFF_W1T = 1u << 20;
  const size_t OFF_W3T = OFF_W1T + ((size_t)EE * DD * HH * 2);
  const size_t OFF_XBF = OFF_W3T + ((size_t)EE * DD * HH * 2);
  const size_t OFF_HB  = OFF_XBF + ((size_t)TT * DD * 2);
  const size_t NEED    = OFF_HB + ((size_t)(2 * TT + 128) * HH * 2);   // ~145.5 MiB

  hipMemsetAsync(ws, 0, 1024, stream);                                  // cpad + ppad

  const bool fast = (ws_size >= NEED);
  short* XBF = fast ? (short*)(ws + OFF_XBF) : nullptr;

  router_kernel<<<256, 256, 0, stream>>>(x, rw, cpad, ppad, list_tok, list_coef, tokpk, tokcf, XBF);
  aux_kernel<<<1, 64, 0, stream>>>(cpad, ppad, offsets, out + (size_t)TT * DD);

  if (fast) {
    short* W13T = (short*)(ws + OFF_W1T);
    short* OB   = (short*)(ws + OFF_W1T);   // aliases experts 0-3 of W13T (free after g1p)
    short* W2T  = (short*)(ws + OFF_W3T);   // aliases experts 4-7 of W13T (free after g1p)
    short* HB   = (short*)(ws + OFF_HB);
    convt13_kernel<<<dim3(HH / 64, DD / 64, 2 * EE), 256, 0, stream>>>(w1, w3, W13T);
    g1p_kernel<<<dim3(16, 32, EE), 512, 0, stream>>>(XBF, W13T, cpad, offsets, list_tok, HB);
    convt_kernel<<<dim3(DD / 64, HH / 64, EE), 256, 0, stream>>>(w2, W2T, HH, DD);
    g2q_kernel<<<dim3(DD / 256, 32, EE), 512, 0, stream>>>(HB, W2T, cpad, offsets, OB);
    combine_kernel<<<TT / 4, 256, 0, stream>>>(OB, offsets, tokpk, tokcf, out);
  } else {
    hipMemsetAsync(d_out, 0, (size_t)TT * DD * sizeof(float), stream);
    short* HB = (short*)(ws + (1 << 20));
    g1s_kernel<<<dim3(HH / 128, TT / 128, EE), 256, 0, stream>>>(x, w1, w3, cpad, offsets, list_tok, HB);
    g2s_kernel<<<dim3(DD / 128, TT / 128, EE), 256, 0, stream>>>(HB, w2, cpad, offsets, list_tok, list_coef, out);
  }
}

// Round 7
// 578.233 us; speedup vs baseline: 1.0246x; 1.0246x over previous
//
#include <hip/hip_runtime.h>
#include <hip/hip_bf16.h>

// Problem constants (B=2, S=4096 -> T=8192 tokens)
#define TT 8192
#define DD 1024
#define HH 2048
#define EE 8

typedef __bf16 bf16x8 __attribute__((ext_vector_type(8)));
typedef float floatx4 __attribute__((ext_vector_type(4)));
typedef short shortx8 __attribute__((ext_vector_type(8)));

// float -> bf16 bits, round-to-nearest-even
__device__ __forceinline__ short f2bf(float f) {
  unsigned u = __float_as_uint(f);
  u += 0x7fffu + ((u >> 16) & 1u);
  return (short)(u >> 16);
}

__device__ __forceinline__ float bf2f(short s) {
  return __uint_as_float(((unsigned)(unsigned short)s) << 16);
}

// async global->LDS, 16B per lane; LDS dest = wave-uniform base + lane*16
__device__ __forceinline__ void gld16(const void* g, void* l) {
  __builtin_amdgcn_global_load_lds((const __attribute__((address_space(1))) void*)g,
                                   (__attribute__((address_space(3))) void*)l, 16, 0, 0);
}

// ================= PREP: router + aux (last-block) + weight conversions, ONE launch ==========
// Block map: [0,256) router; [256,256+8192) convt13 (w1/w3 -> W13T interleaved);
// [256+8192, +4096) convt w2 -> W2T (tier-2 only, dedicated region).
// Launch-overhead theory (r5): ~25-30us per kernel boundary; this merges 3-4 launches into 1
// and overlaps latency-bound router blocks with bandwidth-bound convt blocks.
// No inter-block waits anywhere: the aux finalize is fire-and-forget in whichever router
// block increments ctr to 256 (device-scope atomics; dispatch-order-independent, G16-safe).
__global__ __launch_bounds__(256) void prep_kernel(
    const float* __restrict__ x, const float* __restrict__ rw,
    const float* __restrict__ w1, const float* __restrict__ w3, const float* __restrict__ w2,
    int* __restrict__ cpad, float* __restrict__ ppad, int* __restrict__ ctr,
    int* __restrict__ offsets, float* __restrict__ out_aux,
    int* __restrict__ list_token, float* __restrict__ list_coef,
    int* __restrict__ tokpk, float* __restrict__ tokcf,
    short* __restrict__ xb, short* __restrict__ w13t, short* __restrict__ w2t)
{
  __shared__ short T[64 * 74];
  __shared__ int   sE0[32], sE1[32], lcnt[EE], sbase[EE], lp0[32], lp1[32];
  __shared__ float sG0[32], sG1[32], sP[EE];
  const int b = blockIdx.x;
  const int tid = threadIdx.x;

  if (b < 256) {
    // ---------------- router ----------------
    if (tid < EE) { sP[tid] = 0.f; lcnt[tid] = 0; }
    __syncthreads();
    const int lane = tid & 63, wv = tid >> 6;
    const int t0 = b * 32;
    for (int ti = 0; ti < 8; ++ti) {
      const int s = wv * 8 + ti;
      const int t = t0 + s;
      float sc[EE];
#pragma unroll
      for (int e = 0; e < EE; ++e) sc[e] = 0.f;
#pragma unroll
      for (int j = 0; j < 4; ++j) {
        float4 xv = *(const float4*)(x + (size_t)t * DD + j * 256 + lane * 4);
#pragma unroll
        for (int e = 0; e < EE; ++e) {
          float4 rv = *(const float4*)(rw + e * DD + j * 256 + lane * 4);
          sc[e] += xv.x * rv.x + xv.y * rv.y + xv.z * rv.z + xv.w * rv.w;
        }
        if (xb) {
          short4 sv = make_short4(f2bf(xv.x), f2bf(xv.y), f2bf(xv.z), f2bf(xv.w));
          *(short4*)(xb + (size_t)t * DD + j * 256 + lane * 4) = sv;
        }
      }
#pragma unroll
      for (int off = 32; off > 0; off >>= 1)
#pragma unroll
        for (int e = 0; e < EE; ++e)
          sc[e] += __shfl_down(sc[e], off);
      if (lane == 0) {
        int i0 = 0; float l0 = sc[0];
        for (int e = 1; e < EE; ++e) if (sc[e] > l0) { l0 = sc[e]; i0 = e; }
        int i1 = -1; float l1 = -3.4e38f;
        for (int e = 0; e < EE; ++e) if (e != i0 && sc[e] > l1) { l1 = sc[e]; i1 = e; }
        const float g0 = 1.f / (1.f + __expf(l1 - l0));
        float pr[EE]; float sum = 0.f;
        for (int e = 0; e < EE; ++e) { pr[e] = __expf(sc[e] - l0); sum += pr[e]; }
        const float inv = 1.f / sum;
        for (int e = 0; e < EE; ++e) atomicAdd(&sP[e], pr[e] * inv);
        sE0[s] = i0; sE1[s] = i1; sG0[s] = g0; sG1[s] = 1.f - g0;
      }
    }
    __syncthreads();
    if (tid < 32) {
      lp0[tid] = atomicAdd(&lcnt[sE0[tid]], 1);
      lp1[tid] = atomicAdd(&lcnt[sE1[tid]], 1);
    }
    __syncthreads();
    if (tid < EE) {
      sbase[tid] = atomicAdd(&cpad[tid * 16], lcnt[tid]);
      atomicAdd(&ppad[tid * 16], sP[tid]);
    }
    __syncthreads();
    if (tid < 32) {
      int e0 = sE0[tid], e1 = sE1[tid], t = t0 + tid;
      int p0 = sbase[e0] + lp0[tid];
      int p1 = sbase[e1] + lp1[tid];
      list_token[e0 * TT + p0] = t; list_coef[e0 * TT + p0] = sG0[tid];
      list_token[e1 * TT + p1] = t; list_coef[e1 * TT + p1] = sG1[tid];
      tokpk[t * 2]     = (e0 << 13) | p0;  tokcf[t * 2]     = sG0[tid];
      tokpk[t * 2 + 1] = (e1 << 13) | p1;  tokcf[t * 2 + 1] = sG1[tid];
    }
    __syncthreads();
    // last router block finalizes aux loss + offsets (device-scope atomics, fenced)
    if (tid == 0) {
      __threadfence();
      if (atomicAdd(ctr, 1) == 255) {
        float aux = 0.f; int off = 0;
        for (int e = 0; e < EE; ++e) {
          int c   = atomicAdd(&cpad[e * 16], 0);
          float p = atomicAdd(&ppad[e * 16], 0.f);
          aux += ((float)c / (float)TT) * (p / (float)TT);
          offsets[e] = off; off += c;
        }
        *out_aux = aux * (float)EE;
      }
    }
  } else if (b < 256 + 8192) {
    // ---------------- convt13: w1/w3 [D][H] fp32 -> W13T [2H(perm)][D] bf16 ----------------
    const int u = b - 256;
    const int xx = u & 31, yy = (u >> 5) & 15, z = u >> 9;   // x<32, y<16, z<16
    const int is3 = (z >= EE) ? 1 : 0;
    const int e = is3 ? (z - EE) : z;
    const float* in = (is3 ? w3 : w1) + (size_t)e * DD * HH;
    short* o = w13t + (size_t)e * DD * HH * 2;
    const int c0 = xx * 64, r0 = yy * 64;
#pragma unroll
    for (int p = 0; p < 4; ++p) {
      int r = p * 16 + (tid >> 4), c4 = (tid & 15) * 4;
      float4 v = *(const float4*)(in + (size_t)(r0 + r) * HH + c0 + c4);
      short4 s = make_short4(f2bf(v.x), f2bf(v.y), f2bf(v.z), f2bf(v.w));
      *(short4*)&T[r * 74 + c4] = s;
    }
    __syncthreads();
#pragma unroll
    for (int q = 0; q < 2; ++q) {
      int uu = q * 256 + tid;
      int oc = uu >> 3, k8 = (uu & 7) * 8;
      shortx8 s;
#pragma unroll
      for (int j = 0; j < 8; ++j) s[j] = T[(k8 + j) * 74 + oc];
      int c = c0 + oc;
      int grow = 2 * (c & ~31) + (c & 31) + (is3 ? 32 : 0);
      *(shortx8*)&o[(size_t)grow * DD + r0 + k8] = s;
    }
  } else {
    // ---------------- convt w2: [H][D] fp32 -> W2T [D][H] bf16 (tier-2 only) ----------------
    const int v = b - 256 - 8192;
    const int xx = v & 15, yy = (v >> 4) & 31, z = v >> 9;   // x<16, y<32, z<8
    const float* in = w2 + (size_t)z * HH * DD;
    short* o = w2t + (size_t)z * HH * DD;
    const int c0 = xx * 64, r0 = yy * 64;
#pragma unroll
    for (int p = 0; p < 4; ++p) {
      int r = p * 16 + (tid >> 4), c4 = (tid & 15) * 4;
      float4 vv = *(const float4*)(in + (size_t)(r0 + r) * DD + c0 + c4);
      short4 s = make_short4(f2bf(vv.x), f2bf(vv.y), f2bf(vv.z), f2bf(vv.w));
      *(short4*)&T[r * 74 + c4] = s;
    }
    __syncthreads();
#pragma unroll
    for (int q = 0; q < 2; ++q) {
      int uu = q * 256 + tid;
      int oc = uu >> 3, k8 = (uu & 7) * 8;
      shortx8 s;
#pragma unroll
      for (int j = 0; j < 8; ++j) s[j] = T[(k8 + j) * 74 + oc];
      *(shortx8*)&o[(size_t)(c0 + oc) * HH + r0 + k8] = s;
    }
  }
}

// ---------------- generic convert+transpose: in [R][C] fp32 -> out [C][R] bf16 (tier-1 w2) ---
__global__ __launch_bounds__(256) void convt_kernel(const float* __restrict__ in, short* __restrict__ out,
                                                    int R, int C)
{
  __shared__ short T[64 * 74];
  const int t = threadIdx.x;
  in  += (size_t)blockIdx.z * R * C;
  out += (size_t)blockIdx.z * R * C;
  const int c0 = blockIdx.x * 64, r0 = blockIdx.y * 64;
#pragma unroll
  for (int p = 0; p < 4; ++p) {
    int r = p * 16 + (t >> 4), c4 = (t & 15) * 4;
    float4 v = *(const float4*)(in + (size_t)(r0 + r) * C + c0 + c4);
    short4 s = make_short4(f2bf(v.x), f2bf(v.y), f2bf(v.z), f2bf(v.w));
    *(short4*)&T[r * 74 + c4] = s;
  }
  __syncthreads();
#pragma unroll
  for (int q = 0; q < 2; ++q) {
    int u = q * 256 + t;
    int oc = u >> 3, k8 = (u & 7) * 8;
    shortx8 s;
#pragma unroll
    for (int j = 0; j < 8; ++j) s[j] = T[(k8 + j) * 74 + oc];
    *(shortx8*)&out[(size_t)(c0 + oc) * R + r0 + k8] = s;
  }
}

// =================== 8-phase 256x256 BK=64 pipelined MFMA core (r3 form, unchanged) ==========

#define PH_BAR()  { __builtin_amdgcn_s_barrier(); __builtin_amdgcn_sched_barrier(0); }
#define WAITL0()  { asm volatile("s_waitcnt lgkmcnt(0)" ::: "memory"); __builtin_amdgcn_sched_barrier(0); }
#define WAITVN(n) { asm volatile("s_waitcnt vmcnt(" #n ")" ::: "memory"); __builtin_amdgcn_sched_barrier(0); }

template<int NT>
__device__ __forceinline__ void mma_core(char* SM, int tid,
    const char* a00, const char* a01, const char* a10, const char* a11,
    const char* b00, const char* b01, const char* b10, const char* b11,
    floatx4 (&acc)[8][4])
{
  const int lane = tid & 63, w = tid >> 6;
  const int l16 = lane & 15, quad = lane >> 4;
  const int wm = (w >> 2) & 1, wn = w & 3;
  // frag-read swizzle: col bits {4,5,6} ^= row(l16) bits {1,2,0}
  const int cx = (((l16 >> 1) & 1) << 4) | (((l16 >> 2) & 1) << 5) | ((l16 & 1) << 6);
  const int ck0 = (quad * 16) ^ cx;
  const int arb = (wm * 128 + l16) * 128;             // + mi*2048
  const int brb = 32768 + (wn * 64 + l16) * 128;      // + ni*2048
  const int wq = w * 2048;

#define SA_(u,h,p0,p1) { gld16((p0) + (size_t)(u) * 128, SM + (((u) & 1) << 16) + (h) * 16384 + wq); \
                         gld16((p1) + (size_t)(u) * 128, SM + (((u) & 1) << 16) + (h) * 16384 + wq + 1024); }
#define SB_(u,h,p0,p1) { gld16((p0) + (size_t)(u) * 128, SM + (((u) & 1) << 16) + 32768 + (h) * 16384 + wq); \
                         gld16((p1) + (size_t)(u) * 128, SM + (((u) & 1) << 16) + 32768 + (h) * 16384 + wq + 1024); }
#define LA_(mi) { a[mi][0] = *(const bf16x8*)(SM + cur + arb + (mi) * 2048 + ck0); \
                  a[mi][1] = *(const bf16x8*)(SM + cur + arb + (mi) * 2048 + (ck0 ^ 64)); }
#define LB_(ni) { b[ni][0] = *(const bf16x8*)(SM + cur + brb + (ni) * 2048 + ck0); \
                  b[ni][1] = *(const bf16x8*)(SM + cur + brb + (ni) * 2048 + (ck0 ^ 64)); }
#define MM_(mi,ni) { acc[mi][ni] = __builtin_amdgcn_mfma_f32_16x16x32_bf16(a[mi][0], b[ni][0], acc[mi][ni], 0, 0, 0); \
                     acc[mi][ni] = __builtin_amdgcn_mfma_f32_16x16x32_bf16(a[mi][1], b[ni][1], acc[mi][ni], 0, 0, 0); }

  // prologue: tile0 (A0,A1,B0,B1) + tile1 (A0,A1); wait tile0 landed (4 gld16 left in flight)
  SA_(0, 0, a00, a01); SA_(0, 1, a10, a11);
  SB_(0, 0, b00, b01); SB_(0, 1, b10, b11);
  SA_(1, 0, a00, a01); SA_(1, 1, a10, a11);
  WAITVN(4);
  __builtin_amdgcn_s_barrier();
  __builtin_amdgcn_sched_barrier(0);

#pragma unroll 2
  for (int t = 0; t < NT; ++t) {
    const int cur = (t & 1) << 16;
    bf16x8 a[8][2], b[4][2];
    // ---- P1: 12 ds_reads (a0-3, b0-1); stage B.h0(t+1) -> other buffer
    LA_(0) LA_(1) LA_(2) LA_(3) LB_(0) LB_(1)
    if (t + 1 < NT) SB_(t + 1, 0, b00, b01);
    PH_BAR(); WAITL0();
    __builtin_amdgcn_s_setprio(1);
    MM_(0,0) MM_(1,0) MM_(2,0) MM_(3,0) MM_(0,1) MM_(1,1) MM_(2,1) MM_(3,1)
    __builtin_amdgcn_s_setprio(0);
    PH_BAR();
    // ---- P2: 12 ds_reads (a4-7, b2-3); stage B.h1(t+1)
    LA_(4) LA_(5) LA_(6) LA_(7) LB_(2) LB_(3)
    if (t + 1 < NT) SB_(t + 1, 1, b10, b11);
    PH_BAR(); WAITL0();
    __builtin_amdgcn_s_setprio(1);
    MM_(4,2) MM_(5,2) MM_(6,2) MM_(7,2) MM_(4,3) MM_(5,3) MM_(6,3) MM_(7,3)
    __builtin_amdgcn_s_setprio(0);
    PH_BAR();
    // ---- P3: stage A.h0(t+2) into cur buffer
    if (t + 2 < NT) SA_(t + 2, 0, a00, a01);
    PH_BAR();
    __builtin_amdgcn_s_setprio(1);
    MM_(0,2) MM_(1,2) MM_(2,2) MM_(3,2) MM_(0,3) MM_(1,3) MM_(2,3) MM_(3,3)
    __builtin_amdgcn_s_setprio(0);
    PH_BAR();
    // ---- P4: stage A.h1(t+2); counted vmcnt(4)
    if (t + 2 < NT) SA_(t + 2, 1, a10, a11);
    PH_BAR();
    __builtin_amdgcn_s_setprio(1);
    MM_(4,0) MM_(5,0) MM_(6,0) MM_(7,0) MM_(4,1) MM_(5,1) MM_(6,1) MM_(7,1)
    __builtin_amdgcn_s_setprio(0);
    if (t + 2 < NT) { WAITVN(4); } else { WAITVN(0); }
    PH_BAR();
  }
#undef SA_
#undef SB_
#undef LA_
#undef LB_
#undef MM_
}

// ---------------- G1: H = silu(Xg @ w1) * (Xg @ w3), fused via W13T column-pair interleave ----
__global__ __launch_bounds__(512, 2) void g1p_kernel(
    const short* __restrict__ xb, const short* __restrict__ w13t,
    const int* __restrict__ cpad, const int* __restrict__ offsets,
    const int* __restrict__ list_token, short* __restrict__ Hbuf)
{
  const int lin = blockIdx.x + 16 * (blockIdx.y + 32 * blockIdx.z);
  const int xcd = lin & 7, c = lin >> 3;
  const int e = c >> 6, rb = (c >> 1) & 31, nb = (xcd << 1) | (c & 1);
  const int cnt = cpad[e * 16];
  if (rb * 256 >= cnt) return;
  __shared__ char SM[131072];
  const int tid = threadIdx.x;
  const int lane = tid & 63, w = tid >> 6;
  const int srow = lane >> 3;
  // staging-source swizzle matching frag-read swizzle
  const int scol = (((lane ^ (lane >> 4)) & 1) << 4)
                 | ((((lane >> 1) ^ (lane >> 5)) & 1) << 5)
                 | ((((lane >> 2) ^ (lane >> 3)) & 1) << 6);
  const int* lt = list_token + e * TT;
  const char* ap[2][2];
#pragma unroll
  for (int h = 0; h < 2; ++h)
#pragma unroll
    for (int i = 0; i < 2; ++i) {
      int gr = rb * 256 + h * 128 + (w * 2 + i) * 8 + srow;
      int tok = (gr < cnt) ? lt[gr] : lt[0];
      ap[h][i] = (const char*)xb + (size_t)tok * 2048 + scol;
    }
  const char* bb = (const char*)w13t + ((size_t)e * 4096 + nb * 256) * 2048
                 + (size_t)(w * 16 + srow) * 2048 + scol;
  floatx4 acc[8][4] = {};
  mma_core<16>(SM, tid, ap[0][0], ap[0][1], ap[1][0], ap[1][1],
               bb, bb + 8 * 2048, bb + 128 * 2048, bb + 136 * 2048, acc);
  const int off = offsets[e];
  const int l16 = lane & 15, quad = lane >> 4;
  const int wm = (w >> 2) & 1, wn = w & 3;
#pragma unroll
  for (int mi = 0; mi < 8; ++mi)
#pragma unroll
    for (int r = 0; r < 4; ++r) {
      int grow = rb * 256 + wm * 128 + mi * 16 + quad * 4 + r;
      if (grow < cnt) {
        size_t rowbase = (size_t)(off + grow) * HH + nb * 128 + wn * 32;
#pragma unroll
        for (int ni = 0; ni < 2; ++ni) {
          float aa = acc[mi][ni][r], bbv = acc[mi][ni + 2][r];
          float hv = aa / (1.f + __expf(-aa)) * bbv;
          Hbuf[rowbase + ni * 16 + l16] = f2bf(hv);
        }
      }
    }
}

// ---------------- G2: Obuf[slot] = (Hrows @ w2) via the same 256x256 8-phase core -------------
__global__ __launch_bounds__(512, 2) void g2q_kernel(
    const short* __restrict__ Hbuf, const short* __restrict__ w2t,
    const int* __restrict__ cpad, const int* __restrict__ offsets,
    short* __restrict__ Obuf)
{
  const int nb = blockIdx.x, rb = blockIdx.y, e = blockIdx.z;
  const int cnt = cpad[e * 16];
  if (rb * 256 >= cnt) return;
  __shared__ char SM[131072];
  const int tid = threadIdx.x;
  const int lane = tid & 63, w = tid >> 6;
  const int srow = lane >> 3;
  const int scol = (((lane ^ (lane >> 4)) & 1) << 4)
                 | ((((lane >> 1) ^ (lane >> 5)) & 1) << 5)
                 | ((((lane >> 2) ^ (lane >> 3)) & 1) << 6);
  const int off = offsets[e];
  const char* ap[2][2];
#pragma unroll
  for (int h = 0; h < 2; ++h)
#pragma unroll
    for (int i = 0; i < 2; ++i) {
      int gr = rb * 256 + h * 128 + (w * 2 + i) * 8 + srow;
      int cg = (gr < cnt) ? gr : (cnt - 1);
      ap[h][i] = (const char*)Hbuf + (size_t)(off + cg) * 4096 + scol;
    }
  const char* bb = (const char*)w2t + ((size_t)e * DD + nb * 256) * 4096
                 + (size_t)(w * 16 + srow) * 4096 + scol;
  floatx4 acc[8][4] = {};
  mma_core<32>(SM, tid, ap[0][0], ap[0][1], ap[1][0], ap[1][1],
               bb, bb + 8 * 4096, bb + 128 * 4096, bb + 136 * 4096, acc);
  const int l16 = lane & 15, quad = lane >> 4;
  const int wm = (w >> 2) & 1, wn = w & 3;
#pragma unroll
  for (int mi = 0; mi < 8; ++mi)
#pragma unroll
    for (int r = 0; r < 4; ++r) {
      int grow = rb * 256 + wm * 128 + mi * 16 + quad * 4 + r;
      if (grow < cnt) {
        short* orow = Obuf + (size_t)(off + grow) * DD + nb * 256 + wn * 64;
#pragma unroll
        for (int ni = 0; ni < 4; ++ni)
          orow[ni * 16 + l16] = f2bf(acc[mi][ni][r]);
      }
    }
}

// ---------------- Combine: out[t] = c0*Obuf[slot0] + c1*Obuf[slot1] ----------------
__global__ __launch_bounds__(256) void combine_kernel(
    const short* __restrict__ Obuf, const int* __restrict__ offsets,
    const int* __restrict__ tokpk, const float* __restrict__ tokcf,
    float* __restrict__ out)
{
  const int tid = threadIdx.x, lane = tid & 63, wv = tid >> 6;
  const int t = blockIdx.x * 4 + wv;
  const int pk0 = tokpk[t * 2], pk1 = tokpk[t * 2 + 1];
  const float c0 = tokcf[t * 2], c1 = tokcf[t * 2 + 1];
  const size_t r0 = (size_t)(offsets[pk0 >> 13] + (pk0 & 8191)) * DD;
  const size_t r1 = (size_t)(offsets[pk1 >> 13] + (pk1 & 8191)) * DD;
  float* orow = out + (size_t)t * DD;
#pragma unroll
  for (int p = 0; p < 2; ++p) {
    int cidx = p * 512 + lane * 8;
    shortx8 a = *(const shortx8*)(Obuf + r0 + cidx);
    shortx8 b = *(const shortx8*)(Obuf + r1 + cidx);
    float v[8];
#pragma unroll
    for (int j = 0; j < 8; ++j) v[j] = c0 * bf2f(a[j]) + c1 * bf2f(b[j]);
    *(float4*)(orow + cidx)     = make_float4(v[0], v[1], v[2], v[3]);
    *(float4*)(orow + cidx + 4) = make_float4(v[4], v[5], v[6], v[7]);
  }
}

// ================= FALLBACK (proven path, used if ws too small) =================
__global__ __launch_bounds__(256, 2) void g1s_kernel(
    const float* __restrict__ x, const float* __restrict__ w1, const float* __restrict__ w3,
    const int* __restrict__ cpad, const int* __restrict__ offsets,
    const int* __restrict__ list_token, short* __restrict__ Hbuf)
{
  const int e = blockIdx.z, rb = blockIdx.y, nb = blockIdx.x;
  const int cnt = cpad[e * 16];
  if (rb * 128 >= cnt) return;
  __shared__ short Asm[128 * 40];
  __shared__ short B1sm[128 * 40];
  __shared__ short B3sm[128 * 40];
  const int tid = threadIdx.x, lane = tid & 63, wv = tid >> 6;
  const int wm = (wv >> 1) * 64, wn = (wv & 1) * 64;
  const int quad = lane >> 4, l16 = lane & 15;
  floatx4 acc1[4][4] = {{{0.f}}};
  floatx4 acc3[4][4] = {{{0.f}}};
  const int ar = tid >> 3, ak = (tid & 7) * 4;
  const int bp = tid & 63, bq = tid >> 6;
  const int bswz = (bq ^ ((bp >> 2) & 3)) * 8;
  const int bo0 = (2 * bp) * 40 + bswz, bo1 = bo0 + 40;
  int aro[4], bro[4];
#pragma unroll
  for (int mi = 0; mi < 4; ++mi) aro[mi] = (wm + mi * 16 + l16) * 40 + quad * 8;
#pragma unroll
  for (int ni = 0; ni < 4; ++ni) {
    int nl = wn + ni * 16 + l16;
    bro[ni] = nl * 40 + ((quad ^ ((nl >> 3) & 3)) * 8);
  }
  int tok[4];
#pragma unroll
  for (int i = 0; i < 4; ++i) {
    int gr = rb * 128 + ar + 32 * i;
    tok[i] = (gr < cnt) ? list_token[e * TT + gr] : list_token[e * TT];
  }
  const float* w1e = w1 + (size_t)e * DD * HH + (size_t)nb * 128;
  const float* w3e = w3 + (size_t)e * DD * HH + (size_t)nb * 128;
  for (int k0 = 0; k0 < DD; k0 += 32) {
    __syncthreads();
#pragma unroll
    for (int i = 0; i < 4; ++i) {
      int r = ar + 32 * i;
      float4 v = *(const float4*)(x + (size_t)tok[i] * DD + k0 + ak);
      short4 sv = make_short4(f2bf(v.x), f2bf(v.y), f2bf(v.z), f2bf(v.w));
      *(short4*)&Asm[r * 40 + ak] = sv;
    }
    {
      float2 u[8];
#pragma unroll
      for (int j = 0; j < 8; ++j) u[j] = *(const float2*)(w1e + (size_t)(k0 + bq * 8 + j) * HH + 2 * bp);
      shortx8 p0, p1;
#pragma unroll
      for (int j = 0; j < 8; ++j) { p0[j] = f2bf(u[j].x); p1[j] = f2bf(u[j].y); }
      *(shortx8*)&B1sm[bo0] = p0; *(shortx8*)&B1sm[bo1] = p1;
    }
    {
      float2 u[8];
#pragma unroll
      for (int j = 0; j < 8; ++j) u[j] = *(const float2*)(w3e + (size_t)(k0 + bq * 8 + j) * HH + 2 * bp);
      shortx8 p0, p1;
#pragma unroll
      for (int j = 0; j < 8; ++j) { p0[j] = f2bf(u[j].x); p1[j] = f2bf(u[j].y); }
      *(shortx8*)&B3sm[bo0] = p0; *(shortx8*)&B3sm[bo1] = p1;
    }
    __syncthreads();
    bf16x8 af[4], b1f[4], b3f[4];
#pragma unroll
    for (int mi = 0; mi < 4; ++mi) af[mi] = *(const bf16x8*)&Asm[aro[mi]];
#pragma unroll
    for (int ni = 0; ni < 4; ++ni) {
      b1f[ni] = *(const bf16x8*)&B1sm[bro[ni]];
      b3f[ni] = *(const bf16x8*)&B3sm[bro[ni]];
    }
#pragma unroll
    for (int mi = 0; mi < 4; ++mi)
#pragma unroll
      for (int ni = 0; ni < 4; ++ni) {
        acc1[mi][ni] = __builtin_amdgcn_mfma_f32_16x16x32_bf16(af[mi], b1f[ni], acc1[mi][ni], 0, 0, 0);
        acc3[mi][ni] = __builtin_amdgcn_mfma_f32_16x16x32_bf16(af[mi], b3f[ni], acc3[mi][ni], 0, 0, 0);
      }
  }
  const int off = offsets[e];
#pragma unroll
  for (int mi = 0; mi < 4; ++mi)
#pragma unroll
    for (int r = 0; r < 4; ++r) {
      int row = wm + mi * 16 + quad * 4 + r;
      int grow = rb * 128 + row;
      if (grow < cnt) {
        size_t rowbase = (size_t)(off + grow) * HH + (size_t)nb * 128 + wn;
#pragma unroll
        for (int ni = 0; ni < 4; ++ni) {
          float a = acc1[mi][ni][r], b = acc3[mi][ni][r];
          float h = a / (1.f + __expf(-a)) * b;
          Hbuf[rowbase + ni * 16 + l16] = f2bf(h);
        }
      }
    }
}

__global__ __launch_bounds__(256, 2) void g2s_kernel(
    const short* __restrict__ Hbuf, const float* __restrict__ w2,
    const int* __restrict__ cpad, const int* __restrict__ offsets,
    const int* __restrict__ list_token, const float* __restrict__ list_coef,
    float* __restrict__ out)
{
  const int e = blockIdx.z, rb = blockIdx.y, nb = blockIdx.x;
  const int cnt = cpad[e * 16];
  if (rb * 128 >= cnt) return;
  __shared__ short Asm[128 * 40];
  __shared__ short Bsm[128 * 40];
  const int tid = threadIdx.x, lane = tid & 63, wv = tid >> 6;
  const int wm = (wv >> 1) * 64, wn = (wv & 1) * 64;
  const int quad = lane >> 4, l16 = lane & 15;
  floatx4 acc[4][4] = {{{0.f}}};
  const int ar = tid >> 3, ak = (tid & 7) * 4;
  const int bp = tid & 63, bq = tid >> 6;
  const int bswz = (bq ^ ((bp >> 2) & 3)) * 8;
  const int bo0 = (2 * bp) * 40 + bswz, bo1 = bo0 + 40;
  int aro[4], bro[4];
#pragma unroll
  for (int mi = 0; mi < 4; ++mi) aro[mi] = (wm + mi * 16 + l16) * 40 + quad * 8;
#pragma unroll
  for (int ni = 0; ni < 4; ++ni) {
    int nl = wn + ni * 16 + l16;
    bro[ni] = nl * 40 + ((quad ^ ((nl >> 3) & 3)) * 8);
  }
  const int off = offsets[e];
  size_t hrow[4];
#pragma unroll
  for (int i = 0; i < 4; ++i) {
    int gr = rb * 128 + ar + 32 * i;
    int cg = (gr < cnt) ? gr : (cnt - 1);
    hrow[i] = (size_t)(off + cg) * HH;
  }
  const float* w2e = w2 + (size_t)e * HH * DD + (size_t)nb * 128;
  for (int k0 = 0; k0 < HH; k0 += 32) {
    __syncthreads();
#pragma unroll
    for (int i = 0; i < 4; ++i) {
      int r = ar + 32 * i;
      short4 sv = *(const short4*)(Hbuf + hrow[i] + k0 + ak);
      *(short4*)&Asm[r * 40 + ak] = sv;
    }
    {
      float2 u[8];
#pragma unroll
      for (int j = 0; j < 8; ++j) u[j] = *(const float2*)(w2e + (size_t)(k0 + bq * 8 + j) * DD + 2 * bp);
      shortx8 p0, p1;
#pragma unroll
      for (int j = 0; j < 8; ++j) { p0[j] = f2bf(u[j].x); p1[j] = f2bf(u[j].y); }
      *(shortx8*)&Bsm[bo0] = p0; *(shortx8*)&Bsm[bo1] = p1;
    }
    __syncthreads();
    bf16x8 af[4], bf[4];
#pragma unroll
    for (int mi = 0; mi < 4; ++mi) af[mi] = *(const bf16x8*)&Asm[aro[mi]];
#pragma unroll
    for (int ni = 0; ni < 4; ++ni) bf[ni] = *(const bf16x8*)&Bsm[bro[ni]];
#pragma unroll
    for (int mi = 0; mi < 4; ++mi)
#pragma unroll
      for (int ni = 0; ni < 4; ++ni)
        acc[mi][ni] = __builtin_amdgcn_mfma_f32_16x16x32_bf16(af[mi], bf[ni], acc[mi][ni], 0, 0, 0);
  }
#pragma unroll
  for (int mi = 0; mi < 4; ++mi)
#pragma unroll
    for (int r = 0; r < 4; ++r) {
      int row = wm + mi * 16 + quad * 4 + r;
      int grow = rb * 128 + row;
      if (grow < cnt) {
        int tokid = list_token[e * TT + grow];
        float coef = list_coef[e * TT + grow];
        float* orow = out + (size_t)tokid * DD + (size_t)nb * 128 + wn;
#pragma unroll
        for (int ni = 0; ni < 4; ++ni)
          atomicAdd(&orow[ni * 16 + l16], coef * acc[mi][ni][r]);
      }
    }
}

extern "C" void kernel_launch(void* const* d_in, const int* in_sizes, int n_in,
                              void* d_out, int out_size, void* d_ws, size_t ws_size,
                              hipStream_t stream)
{
  const float* x  = (const float*)d_in[0];
  const float* rw = (const float*)d_in[1];
  const float* w1 = (const float*)d_in[2];
  const float* w3 = (const float*)d_in[3];
  const float* w2 = (const float*)d_in[4];
  float* out = (float*)d_out;

  char* ws = (char*)d_ws;
  int*   cpad      = (int*)(ws + 0);
  float* ppad      = (float*)(ws + 512);
  int*   offsets   = (int*)(ws + 1024);
  int*   ctr       = (int*)(ws + 2048);
  int*   list_tok  = (int*)(ws + 4096);
  float* list_coef = (float*)(ws + 4096 + EE * TT * 4);
  int*   tokpk     = (int*)(ws + 4096 + 2 * EE * TT * 4);
  float* tokcf     = (float*)(ws + 4096 + 2 * EE * TT * 4 + 2 * TT * 4);

  // layout (bytes): hdr 1MB | W13T 64MB | XBF 16MB | HBUF 64.5MB | [tier-2: W2T 32MB]
  // Tier-1 aliasing after g1p: W13T experts 0-3 -> Obuf; experts 4-7 -> W2T.
  // Tier-2: dedicated W2T past HBUF -> w2 conversion folds into prep (one launch).
  const size_t OFF_W1T = 1u << 20;
  const size_t OFF_W3T = OFF_W1T + ((size_t)EE * DD * HH * 2);
  const size_t OFF_XBF = OFF_W3T + ((size_t)EE * DD * HH * 2);
  const size_t OFF_HB  = OFF_XBF + ((size_t)TT * DD * 2);
  const size_t NEED    = OFF_HB + ((size_t)(2 * TT + 128) * HH * 2);   // ~145.5 MiB
  const size_t OFF_W2T = NEED;
  const size_t NEED2   = NEED + ((size_t)EE * DD * HH * 2);            // ~177.5 MiB

  hipMemsetAsync(ws, 0, 4096, stream);   // cpad + ppad + offsets + ctr

  const bool fast  = (ws_size >= NEED);
  const bool tier2 = (ws_size >= NEED2);
  short* XBF = fast ? (short*)(ws + OFF_XBF) : nullptr;

  if (fast) {
    short* W13T = (short*)(ws + OFF_W1T);
    short* OB   = (short*)(ws + OFF_W1T);   // aliases experts 0-3 of W13T (free after g1p)
    short* W2T  = tier2 ? (short*)(ws + OFF_W2T) : (short*)(ws + OFF_W3T);
    short* HB   = (short*)(ws + OFF_HB);
    const int nblk = 256 + 8192 + (tier2 ? 4096 : 0);
    prep_kernel<<<nblk, 256, 0, stream>>>(x, rw, w1, w3, w2, cpad, ppad, ctr, offsets,
                                          out + (size_t)TT * DD, list_tok, list_coef,
                                          tokpk, tokcf, XBF, W13T, W2T);
    g1p_kernel<<<dim3(16, 32, EE), 512, 0, stream>>>(XBF, W13T, cpad, offsets, list_tok, HB);
    if (!tier2)   // W2T aliases W13T experts 4-7: convert only after g1p consumed them
      convt_kernel<<<dim3(DD / 64, HH / 64, EE), 256, 0, stream>>>(w2, W2T, HH, DD);
    g2q_kernel<<<dim3(DD / 256, 32, EE), 512, 0, stream>>>(HB, W2T, cpad, offsets, OB);
    combine_kernel<<<TT / 4, 256, 0, stream>>>(OB, offsets, tokpk, tokcf, out);
  } else {
    hipMemsetAsync(d_out, 0, (size_t)TT * DD * sizeof(float), stream);
    short* HB = (short*)(ws + (1 << 20));
    prep_kernel<<<256, 256, 0, stream>>>(x, rw, w1, w3, w2, cpad, ppad, ctr, offsets,
                                         out + (size_t)TT * DD, list_tok, list_coef,
                                         tokpk, tokcf, nullptr, nullptr, nullptr);
    g1s_kernel<<<dim3(HH / 128, TT / 128, EE), 256, 0, stream>>>(x, w1, w3, cpad, offsets, list_tok, HB);
    g2s_kernel<<<dim3(DD / 128, TT / 128, EE), 256, 0, stream>>>(HB, w2, cpad, offsets, list_tok, list_coef, out);
  }
}

// Round 8
// 572.855 us; speedup vs baseline: 1.0342x; 1.0094x over previous
//
#include <hip/hip_runtime.h>
#include <hip/hip_bf16.h>

// Problem constants (B=2, S=4096 -> T=8192 tokens)
#define TT 8192
#define DD 1024
#define HH 2048
#define EE 8

typedef __bf16 bf16x8 __attribute__((ext_vector_type(8)));
typedef float floatx4 __attribute__((ext_vector_type(4)));
typedef short shortx8 __attribute__((ext_vector_type(8)));

// float -> bf16 bits, round-to-nearest-even
__device__ __forceinline__ short f2bf(float f) {
  unsigned u = __float_as_uint(f);
  u += 0x7fffu + ((u >> 16) & 1u);
  return (short)(u >> 16);
}

__device__ __forceinline__ float bf2f(short s) {
  return __uint_as_float(((unsigned)(unsigned short)s) << 16);
}

// async global->LDS, 16B per lane; LDS dest = wave-uniform base + lane*16
__device__ __forceinline__ void gld16(const void* g, void* l) {
  __builtin_amdgcn_global_load_lds((const __attribute__((address_space(1))) void*)g,
                                   (__attribute__((address_space(3))) void*)l, 16, 0, 0);
}

// ================= PREP: router + aux (last-block) + weight conversions, ONE launch ==========
__global__ __launch_bounds__(256) void prep_kernel(
    const float* __restrict__ x, const float* __restrict__ rw,
    const float* __restrict__ w1, const float* __restrict__ w3, const float* __restrict__ w2,
    int* __restrict__ cpad, float* __restrict__ ppad, int* __restrict__ ctr,
    int* __restrict__ offsets, float* __restrict__ out_aux,
    int* __restrict__ list_token, float* __restrict__ list_coef,
    int* __restrict__ tokpk, float* __restrict__ tokcf,
    short* __restrict__ xb, short* __restrict__ w13t, short* __restrict__ w2t)
{
  __shared__ short T[64 * 74];
  __shared__ int   sE0[32], sE1[32], lcnt[EE], sbase[EE], lp0[32], lp1[32];
  __shared__ float sG0[32], sG1[32], sP[EE];
  const int b = blockIdx.x;
  const int tid = threadIdx.x;

  if (b < 256) {
    // ---------------- router ----------------
    if (tid < EE) { sP[tid] = 0.f; lcnt[tid] = 0; }
    __syncthreads();
    const int lane = tid & 63, wv = tid >> 6;
    const int t0 = b * 32;
    for (int ti = 0; ti < 8; ++ti) {
      const int s = wv * 8 + ti;
      const int t = t0 + s;
      float sc[EE];
#pragma unroll
      for (int e = 0; e < EE; ++e) sc[e] = 0.f;
#pragma unroll
      for (int j = 0; j < 4; ++j) {
        float4 xv = *(const float4*)(x + (size_t)t * DD + j * 256 + lane * 4);
#pragma unroll
        for (int e = 0; e < EE; ++e) {
          float4 rv = *(const float4*)(rw + e * DD + j * 256 + lane * 4);
          sc[e] += xv.x * rv.x + xv.y * rv.y + xv.z * rv.z + xv.w * rv.w;
        }
        if (xb) {
          short4 sv = make_short4(f2bf(xv.x), f2bf(xv.y), f2bf(xv.z), f2bf(xv.w));
          *(short4*)(xb + (size_t)t * DD + j * 256 + lane * 4) = sv;
        }
      }
#pragma unroll
      for (int off = 32; off > 0; off >>= 1)
#pragma unroll
        for (int e = 0; e < EE; ++e)
          sc[e] += __shfl_down(sc[e], off);
      if (lane == 0) {
        int i0 = 0; float l0 = sc[0];
        for (int e = 1; e < EE; ++e) if (sc[e] > l0) { l0 = sc[e]; i0 = e; }
        int i1 = -1; float l1 = -3.4e38f;
        for (int e = 0; e < EE; ++e) if (e != i0 && sc[e] > l1) { l1 = sc[e]; i1 = e; }
        const float g0 = 1.f / (1.f + __expf(l1 - l0));
        float pr[EE]; float sum = 0.f;
        for (int e = 0; e < EE; ++e) { pr[e] = __expf(sc[e] - l0); sum += pr[e]; }
        const float inv = 1.f / sum;
        for (int e = 0; e < EE; ++e) atomicAdd(&sP[e], pr[e] * inv);
        sE0[s] = i0; sE1[s] = i1; sG0[s] = g0; sG1[s] = 1.f - g0;
      }
    }
    __syncthreads();
    if (tid < 32) {
      lp0[tid] = atomicAdd(&lcnt[sE0[tid]], 1);
      lp1[tid] = atomicAdd(&lcnt[sE1[tid]], 1);
    }
    __syncthreads();
    if (tid < EE) {
      sbase[tid] = atomicAdd(&cpad[tid * 16], lcnt[tid]);
      atomicAdd(&ppad[tid * 16], sP[tid]);
    }
    __syncthreads();
    if (tid < 32) {
      int e0 = sE0[tid], e1 = sE1[tid], t = t0 + tid;
      int p0 = sbase[e0] + lp0[tid];
      int p1 = sbase[e1] + lp1[tid];
      list_token[e0 * TT + p0] = t; list_coef[e0 * TT + p0] = sG0[tid];
      list_token[e1 * TT + p1] = t; list_coef[e1 * TT + p1] = sG1[tid];
      tokpk[t * 2]     = (e0 << 13) | p0;  tokcf[t * 2]     = sG0[tid];
      tokpk[t * 2 + 1] = (e1 << 13) | p1;  tokcf[t * 2 + 1] = sG1[tid];
    }
    __syncthreads();
    if (tid == 0) {
      __threadfence();
      if (atomicAdd(ctr, 1) == 255) {
        float aux = 0.f; int off = 0;
        for (int e = 0; e < EE; ++e) {
          int c   = atomicAdd(&cpad[e * 16], 0);
          float p = atomicAdd(&ppad[e * 16], 0.f);
          aux += ((float)c / (float)TT) * (p / (float)TT);
          offsets[e] = off; off += c;
        }
        *out_aux = aux * (float)EE;
      }
    }
  } else if (b < 256 + 8192) {
    // ---------------- convt13: w1/w3 [D][H] fp32 -> W13T [2H(perm)][D] bf16 ----------------
    const int u = b - 256;
    const int xx = u & 31, yy = (u >> 5) & 15, z = u >> 9;
    const int is3 = (z >= EE) ? 1 : 0;
    const int e = is3 ? (z - EE) : z;
    const float* in = (is3 ? w3 : w1) + (size_t)e * DD * HH;
    short* o = w13t + (size_t)e * DD * HH * 2;
    const int c0 = xx * 64, r0 = yy * 64;
#pragma unroll
    for (int p = 0; p < 4; ++p) {
      int r = p * 16 + (tid >> 4), c4 = (tid & 15) * 4;
      float4 v = *(const float4*)(in + (size_t)(r0 + r) * HH + c0 + c4);
      short4 s = make_short4(f2bf(v.x), f2bf(v.y), f2bf(v.z), f2bf(v.w));
      *(short4*)&T[r * 74 + c4] = s;
    }
    __syncthreads();
#pragma unroll
    for (int q = 0; q < 2; ++q) {
      int uu = q * 256 + tid;
      int oc = uu >> 3, k8 = (uu & 7) * 8;
      shortx8 s;
#pragma unroll
      for (int j = 0; j < 8; ++j) s[j] = T[(k8 + j) * 74 + oc];
      int c = c0 + oc;
      int grow = 2 * (c & ~31) + (c & 31) + (is3 ? 32 : 0);
      *(shortx8*)&o[(size_t)grow * DD + r0 + k8] = s;
    }
  } else {
    // ---------------- convt w2: [H][D] fp32 -> W2T [D][H] bf16 (tier-2 only) ----------------
    const int v = b - 256 - 8192;
    const int xx = v & 15, yy = (v >> 4) & 31, z = v >> 9;
    const float* in = w2 + (size_t)z * HH * DD;
    short* o = w2t + (size_t)z * HH * DD;
    const int c0 = xx * 64, r0 = yy * 64;
#pragma unroll
    for (int p = 0; p < 4; ++p) {
      int r = p * 16 + (tid >> 4), c4 = (tid & 15) * 4;
      float4 vv = *(const float4*)(in + (size_t)(r0 + r) * DD + c0 + c4);
      short4 s = make_short4(f2bf(vv.x), f2bf(vv.y), f2bf(vv.z), f2bf(vv.w));
      *(short4*)&T[r * 74 + c4] = s;
    }
    __syncthreads();
#pragma unroll
    for (int q = 0; q < 2; ++q) {
      int uu = q * 256 + tid;
      int oc = uu >> 3, k8 = (uu & 7) * 8;
      shortx8 s;
#pragma unroll
      for (int j = 0; j < 8; ++j) s[j] = T[(k8 + j) * 74 + oc];
      *(shortx8*)&o[(size_t)(c0 + oc) * HH + r0 + k8] = s;
    }
  }
}

// ---------------- generic convert+transpose: in [R][C] fp32 -> out [C][R] bf16 (tier-1 w2) ---
__global__ __launch_bounds__(256) void convt_kernel(const float* __restrict__ in, short* __restrict__ out,
                                                    int R, int C)
{
  __shared__ short T[64 * 74];
  const int t = threadIdx.x;
  in  += (size_t)blockIdx.z * R * C;
  out += (size_t)blockIdx.z * R * C;
  const int c0 = blockIdx.x * 64, r0 = blockIdx.y * 64;
#pragma unroll
  for (int p = 0; p < 4; ++p) {
    int r = p * 16 + (t >> 4), c4 = (t & 15) * 4;
    float4 v = *(const float4*)(in + (size_t)(r0 + r) * C + c0 + c4);
    short4 s = make_short4(f2bf(v.x), f2bf(v.y), f2bf(v.z), f2bf(v.w));
    *(short4*)&T[r * 74 + c4] = s;
  }
  __syncthreads();
#pragma unroll
  for (int q = 0; q < 2; ++q) {
    int u = q * 256 + t;
    int oc = u >> 3, k8 = (u & 7) * 8;
    shortx8 s;
#pragma unroll
    for (int j = 0; j < 8; ++j) s[j] = T[(k8 + j) * 74 + oc];
    *(shortx8*)&out[(size_t)(c0 + oc) * R + r0 + k8] = s;
  }
}

// =================== 256x256 BK=64 MFMA core, v2: ROTATED frag reads =========================
// Change vs r3-r7 core: ds_reads issue inside the MFMA shadow instead of bursting before their
// own lgkmcnt(0). Quadrant order Q1(a0-3,b0-1) Q2(a0-3,b2-3) Q3(a4-7,b2-3) Q4(a4-7,b0-1) so
// a0-3 dies after Q2, letting P3 pre-read next tile's a0-3 from the other buffer under Q3.
// vmcnt bookkeeping (8 gld16 issued/tile: P2 SBx4, P3 SAx2, P4 SAx2):
//   P3 WAITVN(4): outstanding = SB(k+1)x4 + SA(k+1)x4 -> drains SA(k+1) (oldest) => A(k+1) ready
//   P4 WAITVN(4): outstanding = SB(k+1)x4 + SA(k+2)x4 -> drains SB(k+1)        => B(k+1) ready
// lgkmcnt(0) precedes each s_barrier whose post-barrier code consumes pre-barrier reads (ISA §8).
// Barriers: 2/tile (end-P2 protects cur-A WAR vs P3 staging; end-P4 = tile boundary).

#define PH_BAR()  { __builtin_amdgcn_s_barrier(); __builtin_amdgcn_sched_barrier(0); }
#define WAITL0()  { asm volatile("s_waitcnt lgkmcnt(0)" ::: "memory"); __builtin_amdgcn_sched_barrier(0); }
#define WAITVN(n) { asm volatile("s_waitcnt vmcnt(" #n ")" ::: "memory"); __builtin_amdgcn_sched_barrier(0); }

template<int NT>
__device__ __forceinline__ void mma_core(char* SM, int tid,
    const char* a00, const char* a01, const char* a10, const char* a11,
    const char* b00, const char* b01, const char* b10, const char* b11,
    floatx4 (&acc)[8][4])
{
  const int lane = tid & 63, w = tid >> 6;
  const int l16 = lane & 15, quad = lane >> 4;
  // frag-read swizzle: col bits {4,5,6} ^= row(l16) bits {1,2,0}
  const int cx = (((l16 >> 1) & 1) << 4) | (((l16 >> 2) & 1) << 5) | ((l16 & 1) << 6);
  const int ck0 = (quad * 16) ^ cx;
  const int wm = (w >> 2) & 1;
  const int arb = (wm * 128 + l16) * 128;             // + mi*2048
  const int brb = 32768 + ((w & 3) * 64 + l16) * 128; // + ni*2048
  const int wq = w * 2048;

#define SA_(u,h,p0,p1) { gld16((p0) + (size_t)(u) * 128, SM + (((u) & 1) << 16) + (h) * 16384 + wq); \
                         gld16((p1) + (size_t)(u) * 128, SM + (((u) & 1) << 16) + (h) * 16384 + wq + 1024); }
#define SB_(u,h,p0,p1) { gld16((p0) + (size_t)(u) * 128, SM + (((u) & 1) << 16) + 32768 + (h) * 16384 + wq); \
                         gld16((p1) + (size_t)(u) * 128, SM + (((u) & 1) << 16) + 32768 + (h) * 16384 + wq + 1024); }
#define LA_(mi) { a[mi][0] = *(const bf16x8*)(SM + cur + arb + (mi) * 2048 + ck0); \
                  a[mi][1] = *(const bf16x8*)(SM + cur + arb + (mi) * 2048 + (ck0 ^ 64)); }
#define LAo_(mi) { a[mi][0] = *(const bf16x8*)(SM + oth + arb + (mi) * 2048 + ck0); \
                   a[mi][1] = *(const bf16x8*)(SM + oth + arb + (mi) * 2048 + (ck0 ^ 64)); }
#define LB_(ni) { b[ni][0] = *(const bf16x8*)(SM + cur + brb + (ni) * 2048 + ck0); \
                  b[ni][1] = *(const bf16x8*)(SM + cur + brb + (ni) * 2048 + (ck0 ^ 64)); }
#define MM_(mi,ni) { acc[mi][ni] = __builtin_amdgcn_mfma_f32_16x16x32_bf16(a[mi][0], b[ni][0], acc[mi][ni], 0, 0, 0); \
                     acc[mi][ni] = __builtin_amdgcn_mfma_f32_16x16x32_bf16(a[mi][1], b[ni][1], acc[mi][ni], 0, 0, 0); }

  bf16x8 a[8][2], b[4][2];

  // prologue: stage tile0 (A,B) + tile1 (A); wait tile0 landed (SA(1)x4 left in flight)
  SA_(0, 0, a00, a01); SA_(0, 1, a10, a11);
  SB_(0, 0, b00, b01); SB_(0, 1, b10, b11);
  SA_(1, 0, a00, a01); SA_(1, 1, a10, a11);
  WAITVN(4);
  __builtin_amdgcn_s_barrier();
  __builtin_amdgcn_sched_barrier(0);
  {  // pre-read a0-3 of tile 0 (invariant: entering tile k, a0-3 holds A(k))
    const int cur = 0;
    LA_(0) LA_(1) LA_(2) LA_(3)
  }
  __builtin_amdgcn_sched_barrier(0);

#pragma unroll 2
  for (int t = 0; t < NT; ++t) {
    const int cur = (t & 1) << 16;
    const int oth = cur ^ (1 << 16);
    // ---- P1: issue all cur reads (b0-3, a4-7); Q1 runs while most complete in its shadow
    LB_(0) LB_(1)
    LA_(4) LA_(5) LA_(6) LA_(7)
    LB_(2) LB_(3)
    __builtin_amdgcn_s_setprio(1);
    MM_(0,0) MM_(1,0) MM_(2,0) MM_(3,0) MM_(0,1) MM_(1,1) MM_(2,1) MM_(3,1)   // Q1
    __builtin_amdgcn_s_setprio(0);
    __builtin_amdgcn_sched_barrier(0);
    // ---- P2: stage B(k+1) -> other buffer; Q2
    if (t + 1 < NT) { SB_(t + 1, 0, b00, b01); SB_(t + 1, 1, b10, b11); }
    __builtin_amdgcn_s_setprio(1);
    MM_(0,2) MM_(1,2) MM_(2,2) MM_(3,2) MM_(0,3) MM_(1,3) MM_(2,3) MM_(3,3)   // Q2 (a0-3 dead)
    __builtin_amdgcn_s_setprio(0);
    WAITL0();   // a4-7/b reads drained before barrier (consumed post-barrier; WAR vs P3 staging)
    PH_BAR();
    // ---- P3: A(k+1) confirmed; stage A(k+2).h0 into cur; pre-read next a0-3 from other; Q3
    WAITVN(4);
    if (t + 2 < NT) SA_(t + 2, 0, a00, a01);
    if (t + 1 < NT) { LAo_(0) LAo_(1) LAo_(2) LAo_(3) }
    __builtin_amdgcn_s_setprio(1);
    MM_(4,2) MM_(5,2) MM_(6,2) MM_(7,2) MM_(4,3) MM_(5,3) MM_(6,3) MM_(7,3)   // Q3
    __builtin_amdgcn_s_setprio(0);
    __builtin_amdgcn_sched_barrier(0);
    // ---- P4: stage A(k+2).h1; Q4; counted vmcnt -> B(k+1) landed for next tile
    if (t + 2 < NT) SA_(t + 2, 1, a10, a11);
    __builtin_amdgcn_s_setprio(1);
    MM_(4,0) MM_(5,0) MM_(6,0) MM_(7,0) MM_(4,1) MM_(5,1) MM_(6,1) MM_(7,1)   // Q4 (a4-7 dead)
    __builtin_amdgcn_s_setprio(0);
    WAITL0();   // LAo reads drained before tile-boundary barrier (consumed next tile)
    if (t + 2 < NT) { WAITVN(4); } else { WAITVN(0); }
    PH_BAR();
  }
#undef SA_
#undef SB_
#undef LA_
#undef LAo_
#undef LB_
#undef MM_
}

// ---------------- G1: H = silu(Xg @ w1) * (Xg @ w3), fused via W13T column-pair interleave ----
__global__ __launch_bounds__(512, 2) void g1p_kernel(
    const short* __restrict__ xb, const short* __restrict__ w13t,
    const int* __restrict__ cpad, const int* __restrict__ offsets,
    const int* __restrict__ list_token, short* __restrict__ Hbuf)
{
  const int lin = blockIdx.x + 16 * (blockIdx.y + 32 * blockIdx.z);
  const int xcd = lin & 7, c = lin >> 3;
  const int e = c >> 6, rb = (c >> 1) & 31, nb = (xcd << 1) | (c & 1);
  const int cnt = cpad[e * 16];
  if (rb * 256 >= cnt) return;
  __shared__ char SM[131072];
  const int tid = threadIdx.x;
  const int lane = tid & 63, w = tid >> 6;
  const int srow = lane >> 3;
  // staging-source swizzle matching frag-read swizzle
  const int scol = (((lane ^ (lane >> 4)) & 1) << 4)
                 | ((((lane >> 1) ^ (lane >> 5)) & 1) << 5)
                 | ((((lane >> 2) ^ (lane >> 3)) & 1) << 6);
  const int* lt = list_token + e * TT;
  const char* ap[2][2];
#pragma unroll
  for (int h = 0; h < 2; ++h)
#pragma unroll
    for (int i = 0; i < 2; ++i) {
      int gr = rb * 256 + h * 128 + (w * 2 + i) * 8 + srow;
      int tok = (gr < cnt) ? lt[gr] : lt[0];
      ap[h][i] = (const char*)xb + (size_t)tok * 2048 + scol;
    }
  const char* bb = (const char*)w13t + ((size_t)e * 4096 + nb * 256) * 2048
                 + (size_t)(w * 16 + srow) * 2048 + scol;
  floatx4 acc[8][4] = {};
  mma_core<16>(SM, tid, ap[0][0], ap[0][1], ap[1][0], ap[1][1],
               bb, bb + 8 * 2048, bb + 128 * 2048, bb + 136 * 2048, acc);
  const int off = offsets[e];
  const int l16 = lane & 15, quad = lane >> 4;
  const int wm = (w >> 2) & 1, wn = w & 3;
#pragma unroll
  for (int mi = 0; mi < 8; ++mi)
#pragma unroll
    for (int r = 0; r < 4; ++r) {
      int grow = rb * 256 + wm * 128 + mi * 16 + quad * 4 + r;
      if (grow < cnt) {
        size_t rowbase = (size_t)(off + grow) * HH + nb * 128 + wn * 32;
#pragma unroll
        for (int ni = 0; ni < 2; ++ni) {
          float aa = acc[mi][ni][r], bbv = acc[mi][ni + 2][r];
          float hv = aa / (1.f + __expf(-aa)) * bbv;
          Hbuf[rowbase + ni * 16 + l16] = f2bf(hv);
        }
      }
    }
}

// ---------------- G2: Obuf[slot] = (Hrows @ w2) via the same core -------------
__global__ __launch_bounds__(512, 2) void g2q_kernel(
    const short* __restrict__ Hbuf, const short* __restrict__ w2t,
    const int* __restrict__ cpad, const int* __restrict__ offsets,
    short* __restrict__ Obuf)
{
  const int nb = blockIdx.x, rb = blockIdx.y, e = blockIdx.z;
  const int cnt = cpad[e * 16];
  if (rb * 256 >= cnt) return;
  __shared__ char SM[131072];
  const int tid = threadIdx.x;
  const int lane = tid & 63, w = tid >> 6;
  const int srow = lane >> 3;
  const int scol = (((lane ^ (lane >> 4)) & 1) << 4)
                 | ((((lane >> 1) ^ (lane >> 5)) & 1) << 5)
                 | ((((lane >> 2) ^ (lane >> 3)) & 1) << 6);
  const int off = offsets[e];
  const char* ap[2][2];
#pragma unroll
  for (int h = 0; h < 2; ++h)
#pragma unroll
    for (int i = 0; i < 2; ++i) {
      int gr = rb * 256 + h * 128 + (w * 2 + i) * 8 + srow;
      int cg = (gr < cnt) ? gr : (cnt - 1);
      ap[h][i] = (const char*)Hbuf + (size_t)(off + cg) * 4096 + scol;
    }
  const char* bb = (const char*)w2t + ((size_t)e * DD + nb * 256) * 4096
                 + (size_t)(w * 16 + srow) * 4096 + scol;
  floatx4 acc[8][4] = {};
  mma_core<32>(SM, tid, ap[0][0], ap[0][1], ap[1][0], ap[1][1],
               bb, bb + 8 * 4096, bb + 128 * 4096, bb + 136 * 4096, acc);
  const int l16 = lane & 15, quad = lane >> 4;
  const int wm = (w >> 2) & 1, wn = w & 3;
#pragma unroll
  for (int mi = 0; mi < 8; ++mi)
#pragma unroll
    for (int r = 0; r < 4; ++r) {
      int grow = rb * 256 + wm * 128 + mi * 16 + quad * 4 + r;
      if (grow < cnt) {
        short* orow = Obuf + (size_t)(off + grow) * DD + nb * 256 + wn * 64;
#pragma unroll
        for (int ni = 0; ni < 4; ++ni)
          orow[ni * 16 + l16] = f2bf(acc[mi][ni][r]);
      }
    }
}

// ---------------- Combine: out[t] = c0*Obuf[slot0] + c1*Obuf[slot1] ----------------
__global__ __launch_bounds__(256) void combine_kernel(
    const short* __restrict__ Obuf, const int* __restrict__ offsets,
    const int* __restrict__ tokpk, const float* __restrict__ tokcf,
    float* __restrict__ out)
{
  const int tid = threadIdx.x, lane = tid & 63, wv = tid >> 6;
  const int t = blockIdx.x * 4 + wv;
  const int pk0 = tokpk[t * 2], pk1 = tokpk[t * 2 + 1];
  const float c0 = tokcf[t * 2], c1 = tokcf[t * 2 + 1];
  const size_t r0 = (size_t)(offsets[pk0 >> 13] + (pk0 & 8191)) * DD;
  const size_t r1 = (size_t)(offsets[pk1 >> 13] + (pk1 & 8191)) * DD;
  float* orow = out + (size_t)t * DD;
#pragma unroll
  for (int p = 0; p < 2; ++p) {
    int cidx = p * 512 + lane * 8;
    shortx8 a = *(const shortx8*)(Obuf + r0 + cidx);
    shortx8 b = *(const shortx8*)(Obuf + r1 + cidx);
    float v[8];
#pragma unroll
    for (int j = 0; j < 8; ++j) v[j] = c0 * bf2f(a[j]) + c1 * bf2f(b[j]);
    *(float4*)(orow + cidx)     = make_float4(v[0], v[1], v[2], v[3]);
    *(float4*)(orow + cidx + 4) = make_float4(v[4], v[5], v[6], v[7]);
  }
}

// ================= FALLBACK (proven path, used if ws too small) =================
__global__ __launch_bounds__(256, 2) void g1s_kernel(
    const float* __restrict__ x, const float* __restrict__ w1, const float* __restrict__ w3,
    const int* __restrict__ cpad, const int* __restrict__ offsets,
    const int* __restrict__ list_token, short* __restrict__ Hbuf)
{
  const int e = blockIdx.z, rb = blockIdx.y, nb = blockIdx.x;
  const int cnt = cpad[e * 16];
  if (rb * 128 >= cnt) return;
  __shared__ short Asm[128 * 40];
  __shared__ short B1sm[128 * 40];
  __shared__ short B3sm[128 * 40];
  const int tid = threadIdx.x, lane = tid & 63, wv = tid >> 6;
  const int wm = (wv >> 1) * 64, wn = (wv & 1) * 64;
  const int quad = lane >> 4, l16 = lane & 15;
  floatx4 acc1[4][4] = {{{0.f}}};
  floatx4 acc3[4][4] = {{{0.f}}};
  const int ar = tid >> 3, ak = (tid & 7) * 4;
  const int bp = tid & 63, bq = tid >> 6;
  const int bswz = (bq ^ ((bp >> 2) & 3)) * 8;
  const int bo0 = (2 * bp) * 40 + bswz, bo1 = bo0 + 40;
  int aro[4], bro[4];
#pragma unroll
  for (int mi = 0; mi < 4; ++mi) aro[mi] = (wm + mi * 16 + l16) * 40 + quad * 8;
#pragma unroll
  for (int ni = 0; ni < 4; ++ni) {
    int nl = wn + ni * 16 + l16;
    bro[ni] = nl * 40 + ((quad ^ ((nl >> 3) & 3)) * 8);
  }
  int tok[4];
#pragma unroll
  for (int i = 0; i < 4; ++i) {
    int gr = rb * 128 + ar + 32 * i;
    tok[i] = (gr < cnt) ? list_token[e * TT + gr] : list_token[e * TT];
  }
  const float* w1e = w1 + (size_t)e * DD * HH + (size_t)nb * 128;
  const float* w3e = w3 + (size_t)e * DD * HH + (size_t)nb * 128;
  for (int k0 = 0; k0 < DD; k0 += 32) {
    __syncthreads();
#pragma unroll
    for (int i = 0; i < 4; ++i) {
      int r = ar + 32 * i;
      float4 v = *(const float4*)(x + (size_t)tok[i] * DD + k0 + ak);
      short4 sv = make_short4(f2bf(v.x), f2bf(v.y), f2bf(v.z), f2bf(v.w));
      *(short4*)&Asm[r * 40 + ak] = sv;
    }
    {
      float2 u[8];
#pragma unroll
      for (int j = 0; j < 8; ++j) u[j] = *(const float2*)(w1e + (size_t)(k0 + bq * 8 + j) * HH + 2 * bp);
      shortx8 p0, p1;
#pragma unroll
      for (int j = 0; j < 8; ++j) { p0[j] = f2bf(u[j].x); p1[j] = f2bf(u[j].y); }
      *(shortx8*)&B1sm[bo0] = p0; *(shortx8*)&B1sm[bo1] = p1;
    }
    {
      float2 u[8];
#pragma unroll
      for (int j = 0; j < 8; ++j) u[j] = *(const float2*)(w3e + (size_t)(k0 + bq * 8 + j) * HH + 2 * bp);
      shortx8 p0, p1;
#pragma unroll
      for (int j = 0; j < 8; ++j) { p0[j] = f2bf(u[j].x); p1[j] = f2bf(u[j].y); }
      *(shortx8*)&B3sm[bo0] = p0; *(shortx8*)&B3sm[bo1] = p1;
    }
    __syncthreads();
    bf16x8 af[4], b1f[4], b3f[4];
#pragma unroll
    for (int mi = 0; mi < 4; ++mi) af[mi] = *(const bf16x8*)&Asm[aro[mi]];
#pragma unroll
    for (int ni = 0; ni < 4; ++ni) {
      b1f[ni] = *(const bf16x8*)&B1sm[bro[ni]];
      b3f[ni] = *(const bf16x8*)&B3sm[bro[ni]];
    }
#pragma unroll
    for (int mi = 0; mi < 4; ++mi)
#pragma unroll
      for (int ni = 0; ni < 4; ++ni) {
        acc1[mi][ni] = __builtin_amdgcn_mfma_f32_16x16x32_bf16(af[mi], b1f[ni], acc1[mi][ni], 0, 0, 0);
        acc3[mi][ni] = __builtin_amdgcn_mfma_f32_16x16x32_bf16(af[mi], b3f[ni], acc3[mi][ni], 0, 0, 0);
      }
  }
  const int off = offsets[e];
#pragma unroll
  for (int mi = 0; mi < 4; ++mi)
#pragma unroll
    for (int r = 0; r < 4; ++r) {
      int row = wm + mi * 16 + quad * 4 + r;
      int grow = rb * 128 + row;
      if (grow < cnt) {
        size_t rowbase = (size_t)(off + grow) * HH + (size_t)nb * 128 + wn;
#pragma unroll
        for (int ni = 0; ni < 4; ++ni) {
          float a = acc1[mi][ni][r], b = acc3[mi][ni][r];
          float h = a / (1.f + __expf(-a)) * b;
          Hbuf[rowbase + ni * 16 + l16] = f2bf(h);
        }
      }
    }
}

__global__ __launch_bounds__(256, 2) void g2s_kernel(
    const short* __restrict__ Hbuf, const float* __restrict__ w2,
    const int* __restrict__ cpad, const int* __restrict__ offsets,
    const int* __restrict__ list_token, const float* __restrict__ list_coef,
    float* __restrict__ out)
{
  const int e = blockIdx.z, rb = blockIdx.y, nb = blockIdx.x;
  const int cnt = cpad[e * 16];
  if (rb * 128 >= cnt) return;
  __shared__ short Asm[128 * 40];
  __shared__ short Bsm[128 * 40];
  const int tid = threadIdx.x, lane = tid & 63, wv = tid >> 6;
  const int wm = (wv >> 1) * 64, wn = (wv & 1) * 64;
  const int quad = lane >> 4, l16 = lane & 15;
  floatx4 acc[4][4] = {{{0.f}}};
  const int ar = tid >> 3, ak = (tid & 7) * 4;
  const int bp = tid & 63, bq = tid >> 6;
  const int bswz = (bq ^ ((bp >> 2) & 3)) * 8;
  const int bo0 = (2 * bp) * 40 + bswz, bo1 = bo0 + 40;
  int aro[4], bro[4];
#pragma unroll
  for (int mi = 0; mi < 4; ++mi) aro[mi] = (wm + mi * 16 + l16) * 40 + quad * 8;
#pragma unroll
  for (int ni = 0; ni < 4; ++ni) {
    int nl = wn + ni * 16 + l16;
    bro[ni] = nl * 40 + ((quad ^ ((nl >> 3) & 3)) * 8);
  }
  const int off = offsets[e];
  size_t hrow[4];
#pragma unroll
  for (int i = 0; i < 4; ++i) {
    int gr = rb * 128 + ar + 32 * i;
    int cg = (gr < cnt) ? gr : (cnt - 1);
    hrow[i] = (size_t)(off + cg) * HH;
  }
  const float* w2e = w2 + (size_t)e * HH * DD + (size_t)nb * 128;
  for (int k0 = 0; k0 < HH; k0 += 32) {
    __syncthreads();
#pragma unroll
    for (int i = 0; i < 4; ++i) {
      int r = ar + 32 * i;
      short4 sv = *(const short4*)(Hbuf + hrow[i] + k0 + ak);
      *(short4*)&Asm[r * 40 + ak] = sv;
    }
    {
      float2 u[8];
#pragma unroll
      for (int j = 0; j < 8; ++j) u[j] = *(const float2*)(w2e + (size_t)(k0 + bq * 8 + j) * DD + 2 * bp);
      shortx8 p0, p1;
#pragma unroll
      for (int j = 0; j < 8; ++j) { p0[j] = f2bf(u[j].x); p1[j] = f2bf(u[j].y); }
      *(shortx8*)&Bsm[bo0] = p0; *(shortx8*)&Bsm[bo1] = p1;
    }
    __syncthreads();
    bf16x8 af[4], bf[4];
#pragma unroll
    for (int mi = 0; mi < 4; ++mi) af[mi] = *(const bf16x8*)&Asm[aro[mi]];
#pragma unroll
    for (int ni = 0; ni < 4; ++ni) bf[ni] = *(const bf16x8*)&Bsm[bro[ni]];
#pragma unroll
    for (int mi = 0; mi < 4; ++mi)
#pragma unroll
      for (int ni = 0; ni < 4; ++ni)
        acc[mi][ni] = __builtin_amdgcn_mfma_f32_16x16x32_bf16(af[mi], bf[ni], acc[mi][ni], 0, 0, 0);
  }
#pragma unroll
  for (int mi = 0; mi < 4; ++mi)
#pragma unroll
    for (int r = 0; r < 4; ++r) {
      int row = wm + mi * 16 + quad * 4 + r;
      int grow = rb * 128 + row;
      if (grow < cnt) {
        int tokid = list_token[e * TT + grow];
        float coef = list_coef[e * TT + grow];
        float* orow = out + (size_t)tokid * DD + (size_t)nb * 128 + wn;
#pragma unroll
        for (int ni = 0; ni < 4; ++ni)
          atomicAdd(&orow[ni * 16 + l16], coef * acc[mi][ni][r]);
      }
    }
}

extern "C" void kernel_launch(void* const* d_in, const int* in_sizes, int n_in,
                              void* d_out, int out_size, void* d_ws, size_t ws_size,
                              hipStream_t stream)
{
  const float* x  = (const float*)d_in[0];
  const float* rw = (const float*)d_in[1];
  const float* w1 = (const float*)d_in[2];
  const float* w3 = (const float*)d_in[3];
  const float* w2 = (const float*)d_in[4];
  float* out = (float*)d_out;

  char* ws = (char*)d_ws;
  int*   cpad      = (int*)(ws + 0);
  float* ppad      = (float*)(ws + 512);
  int*   offsets   = (int*)(ws + 1024);
  int*   ctr       = (int*)(ws + 2048);
  int*   list_tok  = (int*)(ws + 4096);
  float* list_coef = (float*)(ws + 4096 + EE * TT * 4);
  int*   tokpk     = (int*)(ws + 4096 + 2 * EE * TT * 4);
  float* tokcf     = (float*)(ws + 4096 + 2 * EE * TT * 4 + 2 * TT * 4);

  const size_t OFF_W1T = 1u << 20;
  const size_t OFF_W3T = OFF_W1T + ((size_t)EE * DD * HH * 2);
  const size_t OFF_XBF = OFF_W3T + ((size_t)EE * DD * HH * 2);
  const size_t OFF_HB  = OFF_XBF + ((size_t)TT * DD * 2);
  const size_t NEED    = OFF_HB + ((size_t)(2 * TT + 128) * HH * 2);   // ~145.5 MiB
  const size_t OFF_W2T = NEED;
  const size_t NEED2   = NEED + ((size_t)EE * DD * HH * 2);            // ~177.5 MiB

  hipMemsetAsync(ws, 0, 4096, stream);   // cpad + ppad + offsets + ctr

  const bool fast  = (ws_size >= NEED);
  const bool tier2 = (ws_size >= NEED2);
  short* XBF = fast ? (short*)(ws + OFF_XBF) : nullptr;

  if (fast) {
    short* W13T = (short*)(ws + OFF_W1T);
    short* OB   = (short*)(ws + OFF_W1T);   // aliases experts 0-3 of W13T (free after g1p)
    short* W2T  = tier2 ? (short*)(ws + OFF_W2T) : (short*)(ws + OFF_W3T);
    short* HB   = (short*)(ws + OFF_HB);
    const int nblk = 256 + 8192 + (tier2 ? 4096 : 0);
    prep_kernel<<<nblk, 256, 0, stream>>>(x, rw, w1, w3, w2, cpad, ppad, ctr, offsets,
                                          out + (size_t)TT * DD, list_tok, list_coef,
                                          tokpk, tokcf, XBF, W13T, W2T);
    g1p_kernel<<<dim3(16, 32, EE), 512, 0, stream>>>(XBF, W13T, cpad, offsets, list_tok, HB);
    if (!tier2)   // W2T aliases W13T experts 4-7: convert only after g1p consumed them
      convt_kernel<<<dim3(DD / 64, HH / 64, EE), 256, 0, stream>>>(w2, W2T, HH, DD);
    g2q_kernel<<<dim3(DD / 256, 32, EE), 512, 0, stream>>>(HB, W2T, cpad, offsets, OB);
    combine_kernel<<<TT / 4, 256, 0, stream>>>(OB, offsets, tokpk, tokcf, out);
  } else {
    hipMemsetAsync(d_out, 0, (size_t)TT * DD * sizeof(float), stream);
    short* HB = (short*)(ws + (1 << 20));
    prep_kernel<<<256, 256, 0, stream>>>(x, rw, w1, w3, w2, cpad, ppad, ctr, offsets,
                                         out + (size_t)TT * DD, list_tok, list_coef,
                                         tokpk, tokcf, nullptr, nullptr, nullptr);
    g1s_kernel<<<dim3(HH / 128, TT / 128, EE), 256, 0, stream>>>(x, w1, w3, cpad, offsets, list_tok, HB);
    g2s_kernel<<<dim3(DD / 128, TT / 128, EE), 256, 0, stream>>>(HB, w2, cpad, offsets, list_tok, list_coef, out);
  }
}